// Round 11
// baseline (271.233 us; speedup 1.0000x reference)
//
#include <hip/hip_runtime.h>

typedef __attribute__((ext_vector_type(8))) short short8;
typedef __attribute__((ext_vector_type(4))) float f32x4;
typedef unsigned long long u64;

__device__ __forceinline__ unsigned short f2bf(float f) {
  union { float f; unsigned u; } v; v.f = f;
  unsigned u = v.u;
  unsigned r = (u + 0x7FFFu + ((u >> 16) & 1u)) >> 16;  // RTNE
  return (unsigned short)r;
}
__device__ __forceinline__ float bf2f(unsigned short s) {
  union { unsigned u; float f; } v; v.u = ((unsigned)s) << 16;
  return v.f;
}

// packed-tile addressing: operand [rows][K] stored as 8KB tiles of [128][32],
// element (row,col) -> ((row>>7)*(K>>5) + (col>>5))*4096 + (row&127)*32 + (col&31)
__device__ __forceinline__ size_t pkaddr(int row, int col, int K) {
  return ((size_t)(row >> 7) * (K >> 5) + (col >> 5)) * 4096 +
         ((row & 127) << 5) + (col & 31);
}

// async global->LDS, 16B per lane; LDS dest = wave-uniform base + lane*16
__device__ __forceinline__ void gl_lds16(const unsigned short* g, unsigned short* l) {
  __builtin_amdgcn_global_load_lds(
      (const __attribute__((address_space(1))) void*)g,
      (__attribute__((address_space(3))) void*)l, 16, 0, 0);
}

// ---------------- prep: zero deg/cursor + flag + weight transposes ----------------

// transpose one 32x32 tile of src[k][n] into PACKED dst at (rowoff+n, coloff+k)
__device__ __forceinline__ void ttile(const float* __restrict__ src, int Nw,
                                      unsigned short* __restrict__ dst, int Kd,
                                      int rowoff, int coloff,
                                      int tileIdx, int tilesN, float (*tile)[33]) {
  int tk = tileIdx / tilesN, tn = tileIdx % tilesN;
  int k0 = tk * 32, n0 = tn * 32;
  int tx = threadIdx.x & 31, ty = threadIdx.x >> 5;
#pragma unroll
  for (int s = 0; s < 4; ++s)
    tile[ty + s * 8][tx] = src[(size_t)(k0 + ty + s * 8) * Nw + n0 + tx];
  __syncthreads();
#pragma unroll
  for (int s = 0; s < 4; ++s)
    dst[pkaddr(rowoff + n0 + ty + s * 8, coloff + k0 + tx, Kd)] =
        f2bf(tile[tx][ty + s * 8]);
}

__global__ void prep_kernel(int* deg, int* cursor, int n, int* flag,
                            const float* __restrict__ w1_rel, const float* __restrict__ w1_root,
                            const float* __restrict__ w2_rel, const float* __restrict__ w2_root,
                            const float* __restrict__ wmu_rel, const float* __restrict__ wmu_root,
                            const float* __restrict__ wls_rel, const float* __restrict__ wls_root,
                            unsigned short* __restrict__ Bt1,
                            unsigned short* __restrict__ Bt2,
                            unsigned short* __restrict__ Bt3) {
  __shared__ float tile[32][33];
  int b = blockIdx.x;
  if (b >= 1344) {  // 64 init blocks
    int i = (b - 1344) * blockDim.x + threadIdx.x;
    int stride = 64 * blockDim.x;
    for (int j = i; j < n; j += stride) { deg[j] = 0; cursor[j] = 0; }
    if (i == 0) *flag = 1;
    return;
  }
  if (b < 128)       ttile(w1_rel, 1024, Bt1, 256, 0, 0, b, 32, tile);
  else if (b < 256)  ttile(w1_root, 1024, Bt1, 256, 0, 128, b - 128, 32, tile);
  else if (b < 768)  ttile(w2_rel, 512, Bt2, 1024, 0, 0, b - 256, 16, tile);
  else if (b < 1280) ttile(w2_root, 512, Bt2, 1024, 512, 0, b - 768, 16, tile);
  else {
    int idx = (b - 1280) * 256 + threadIdx.x;  // 64 blocks * 256 = 16384 = 32*512
    int nn = idx >> 9, k = idx & 511;
    float v;
    if (nn < 8) v = wmu_rel[(size_t)k * 8 + nn];
    else if (nn < 16) v = wmu_root[(size_t)k * 8 + (nn - 8)];
    else if (nn < 24) v = wls_rel[(size_t)k * 8 + (nn - 16)];
    else v = wls_root[(size_t)k * 8 + (nn - 24)];
    Bt3[(size_t)nn * 512 + k] = f2bf(v);  // Bt3 stays row-major (heads GEMM)
  }
}

// Detect whether edge buffer is int64 (values all in [0,n)) or int32.
__global__ void detect_kernel(const long long* p, int nslots, int n_nodes, int* flag) {
  int i = blockIdx.x * blockDim.x + threadIdx.x;
  if (i < nslots) {
    long long v = p[i];
    if (v < 0 || v >= n_nodes) atomicAnd(flag, 0);
  }
}

__device__ __forceinline__ int edge_at(const void* p, int is64, size_t idx) {
  return is64 ? (int)((const long long*)p)[idx] : ((const int*)p)[idx];
}

__global__ void count_kernel(const void* edges, int E, const int* flag, int* deg) {
  int is64 = *flag;
  int i = blockIdx.x * blockDim.x + threadIdx.x;
  int stride = gridDim.x * blockDim.x;
  for (int e = i; e < E; e += stride) {
    int d = edge_at(edges, is64, (size_t)E + e);
    atomicAdd(&deg[d], 1);
  }
}

__global__ void scan_kernel(const int* __restrict__ deg, int* __restrict__ rs,
                            float* __restrict__ invdeg, int n) {
  __shared__ int ssum[1024];
  int tid = threadIdx.x;
  int chunk = (n + 1023) >> 10;
  int start = tid * chunk;
  int end = min(start + chunk, n);
  int s = 0;
  for (int i = start; i < end; ++i) s += deg[i];
  ssum[tid] = s;
  __syncthreads();
  for (int off = 1; off < 1024; off <<= 1) {
    int t = (tid >= off) ? ssum[tid - off] : 0;
    __syncthreads();
    ssum[tid] += t;
    __syncthreads();
  }
  int run = (tid ? ssum[tid - 1] : 0);
  if (tid == 0) rs[0] = 0;
  for (int i = start; i < end; ++i) {
    int d = deg[i];
    run += d;
    rs[i + 1] = run;
    invdeg[i] = 1.0f / fmaxf((float)d, 1.0f);
  }
}

__global__ void fill_kernel(const void* edges, int E, const int* flag,
                            const int* __restrict__ rs, int* cursor, int* col_src) {
  int is64 = *flag;
  int i = blockIdx.x * blockDim.x + threadIdx.x;
  int stride = gridDim.x * blockDim.x;
  for (int e = i; e < E; e += stride) {
    int d = edge_at(edges, is64, (size_t)E + e);
    int s = edge_at(edges, is64, (size_t)e);
    int p = atomicAdd(&cursor[d], 1);
    col_src[rs[d] + p] = s;
  }
}

// ---------------- aggregation ----------------

// A1 (packed, K=256) = [ bf16(mean_j x_j) | bf16(x_node) ]
__global__ void agg1_kernel(const float* __restrict__ x,
                            const int* __restrict__ rs, const int* __restrict__ cs,
                            const float* __restrict__ invdeg,
                            unsigned short* __restrict__ A1) {
  int node = blockIdx.x;
  int f = threadIdx.x;  // 128
  float xi = x[(size_t)node * 128 + f];
  float acc = 0.f;
  int e1 = rs[node + 1];
  for (int e = rs[node]; e < e1; ++e) {
    acc += x[(size_t)cs[e] * 128 + f];
  }
  A1[pkaddr(node, f, 256)] = f2bf(acc * invdeg[node]);
  A1[pkaddr(node, 128 + f, 256)] = f2bf(xi);
}

// layer-2 combine, 2 nodes/block, 16B per lane (P2 row-major):
// h2[i][c] = relu( inv*sum_j P2[j][c] + P2[i][512+c] + b2[c] )
__global__ void agg2_kernel(const unsigned short* __restrict__ P2,
                            const int* __restrict__ rs, const int* __restrict__ cs,
                            const float* __restrict__ invdeg,
                            const float* __restrict__ b2,
                            unsigned short* __restrict__ h2, int M) {
  int node = blockIdx.x * 2 + (threadIdx.x >> 6);
  if (node >= M) return;
  int f0 = (threadIdx.x & 63) * 8;  // 64 lanes x 8 cols = 512
  float acc[8];
#pragma unroll
  for (int v = 0; v < 8; ++v) acc[v] = 0.f;
  int e1 = rs[node + 1];
  for (int e = rs[node]; e < e1; ++e) {
    int s = cs[e];
    uint4 w = *reinterpret_cast<const uint4*>(P2 + (size_t)s * 1024 + f0);
    acc[0] += bf2f((unsigned short)(w.x & 0xffff));
    acc[1] += bf2f((unsigned short)(w.x >> 16));
    acc[2] += bf2f((unsigned short)(w.y & 0xffff));
    acc[3] += bf2f((unsigned short)(w.y >> 16));
    acc[4] += bf2f((unsigned short)(w.z & 0xffff));
    acc[5] += bf2f((unsigned short)(w.z >> 16));
    acc[6] += bf2f((unsigned short)(w.w & 0xffff));
    acc[7] += bf2f((unsigned short)(w.w >> 16));
  }
  float inv = invdeg[node];
  uint4 wr = *reinterpret_cast<const uint4*>(P2 + (size_t)node * 1024 + 512 + f0);
  float rt[8] = {
    bf2f((unsigned short)(wr.x & 0xffff)), bf2f((unsigned short)(wr.x >> 16)),
    bf2f((unsigned short)(wr.y & 0xffff)), bf2f((unsigned short)(wr.y >> 16)),
    bf2f((unsigned short)(wr.z & 0xffff)), bf2f((unsigned short)(wr.z >> 16)),
    bf2f((unsigned short)(wr.w & 0xffff)), bf2f((unsigned short)(wr.w >> 16))};
  unsigned short o[8];
#pragma unroll
  for (int v = 0; v < 8; ++v)
    o[v] = f2bf(fmaxf(acc[v] * inv + rt[v] + b2[f0 + v], 0.f));
  uint4 pk;
  pk.x = (unsigned)o[0] | ((unsigned)o[1] << 16);
  pk.y = (unsigned)o[2] | ((unsigned)o[3] << 16);
  pk.z = (unsigned)o[4] | ((unsigned)o[5] << 16);
  pk.w = (unsigned)o[6] | ((unsigned)o[7] << 16);
  *reinterpret_cast<uint4*>(h2 + (size_t)node * 512 + f0) = pk;
}

// heads combine: P3 [Mpad][32] f32: cols 0-7 mu_rel, 8-15 mu_root, 16-23 ls_rel, 24-31 ls_root
__global__ void head_agg_kernel(const float* __restrict__ P3,
                                const int* __restrict__ rs, const int* __restrict__ cs,
                                const float* __restrict__ invdeg,
                                const float* __restrict__ bmu, const float* __restrict__ bls,
                                float* __restrict__ outmu, float* __restrict__ outls, int M) {
  int idx = blockIdx.x * blockDim.x + threadIdx.x;
  int node = idx >> 4;
  int c = idx & 15;
  if (node >= M) return;
  int relc = (c < 8) ? c : (16 + (c - 8));
  float acc = 0.f;
  int e1 = rs[node + 1];
  for (int e = rs[node]; e < e1; ++e) acc += P3[(size_t)cs[e] * 32 + relc];
  float v = acc * invdeg[node] + P3[(size_t)node * 32 + relc + 8]
          + ((c < 8) ? bmu[c] : bls[c - 8]);
  if (c < 8) outmu[(size_t)node * 8 + c] = v;
  else outls[(size_t)node * 8 + (c - 8)] = v;
}

// ------ 128x128 GEMM on PACKED operands, 2 tiles/block, ring-2, swizzled ------
// C = A[M][K] * Bt[N][K]^T (+bias)(relu). A,Bt in packed 8KB-tile layout.
// Block processes 2 consecutive tiles (same m-panel, adjacent n-panels).
// Grid = total_tiles/2 <= 4 blocks/CU * 256 -> single balanced round.
// Staging: each gl_lds reads 1KB CONTIGUOUS (wave = 16 rows x 64B of a tile).
// out_pk: 0 = row-major (stride ldo), 1 = packed bf16 with total-K = ldo.
__launch_bounds__(256, 4)
__global__ void gemm_db_kernel(const unsigned short* __restrict__ A,
                               const unsigned short* __restrict__ Bt,
                               const float* __restrict__ bias,
                               void* __restrict__ outp, int ldo,
                               int M, int K, int relu, int out_f32, int out_pk, int gx) {
  __shared__ unsigned short As[2 * 4096];
  __shared__ unsigned short Bs[2 * 4096];
  const int tid = threadIdx.x;
  const int lane = tid & 63;
  const int w = tid >> 6;
  const int wr = w >> 1, wc = w & 1;
  const int lr = lane & 15, lk = lane >> 4;
  const int sw8 = (lk ^ ((lr >> 1) & 3)) * 8;

  // bijective XCD swizzle (m204)
  int nwg = gridDim.x, orig = blockIdx.x;
  int q = nwg >> 3, r = nwg & 7;
  int xcd = orig & 7, lid = orig >> 3;
  int swz = (xcd < r ? xcd * (q + 1) : r * (q + 1) + (xcd - r) * q) + lid;

  // staging: row r0 = tid>>2 (and +64), phys slot = tid&3, swizzled source slot
  const int r0 = tid >> 2;
  const int slog = ((tid & 3) ^ ((r0 >> 1) & 3)) * 8;
  const int thr_off = r0 * 32 + slog;   // within-tile short offset
  const int nt = K >> 5;
  unsigned short* wa = As + w * 512;
  unsigned short* wb = Bs + w * 512;

  for (int tt = 0; tt < 2; ++tt) {
    int tileIdx = swz * 2 + tt;
    int m0 = (tileIdx / gx) * 128, n0 = (tileIdx % gx) * 128;
    const unsigned short* gA = A + (size_t)(m0 >> 7) * nt * 4096 + thr_off;
    const unsigned short* gB = Bt + (size_t)(n0 >> 7) * nt * 4096 + thr_off;

    f32x4 acc[4][4];
#pragma unroll
    for (int i = 0; i < 4; ++i)
#pragma unroll
      for (int j = 0; j < 4; ++j) acc[i][j] = (f32x4)0.0f;

    auto STG = [&](int s, int t) {
      const unsigned short* a = gA + (size_t)t * 4096;
      const unsigned short* b = gB + (size_t)t * 4096;
      gl_lds16(a, wa + s * 4096);
      gl_lds16(a + 2048, wa + s * 4096 + 2048);   // rows 64..127
      gl_lds16(b, wb + s * 4096);
      gl_lds16(b + 2048, wb + s * 4096 + 2048);
    };

    if (tt) __builtin_amdgcn_s_barrier();  // all waves done reading prev tile's LDS
    STG(0, 0);
    asm volatile("s_waitcnt vmcnt(0)" ::: "memory");
    __builtin_amdgcn_s_barrier();

    int buf = 0;
    for (int t = 0; t < nt; ++t) {
      if (t + 1 < nt) STG(buf ^ 1, t + 1);
      const unsigned short* as_ = As + buf * 4096;
      const unsigned short* bs_ = Bs + buf * 4096;
      short8 af[4], bf[4];
#pragma unroll
      for (int i = 0; i < 4; ++i) {
        af[i] = *reinterpret_cast<const short8*>(&as_[(wr * 64 + i * 16 + lr) * 32 + sw8]);
        bf[i] = *reinterpret_cast<const short8*>(&bs_[(wc * 64 + i * 16 + lr) * 32 + sw8]);
      }
      __builtin_amdgcn_s_setprio(1);
#pragma unroll
      for (int i = 0; i < 4; ++i)
#pragma unroll
        for (int j = 0; j < 4; ++j)
          acc[i][j] = __builtin_amdgcn_mfma_f32_16x16x32_bf16(af[i], bf[j], acc[i][j], 0, 0, 0);
      __builtin_amdgcn_s_setprio(0);
      if (t + 1 < nt) {
        asm volatile("s_waitcnt vmcnt(0) lgkmcnt(0)" ::: "memory");
        __builtin_amdgcn_s_barrier();
      }
      buf ^= 1;
    }

#pragma unroll
    for (int i = 0; i < 4; ++i) {
      int row_b = m0 + wr * 64 + i * 16 + lk * 4;
#pragma unroll
      for (int j = 0; j < 4; ++j) {
        int col = n0 + wc * 64 + j * 16 + lr;
        float bv = bias ? bias[col] : 0.f;
#pragma unroll
        for (int rr = 0; rr < 4; ++rr) {
          int row = row_b + rr;
          if (row < M) {
            float v = acc[i][j][rr] + bv;
            if (relu) v = fmaxf(v, 0.f);
            if (out_f32) ((float*)outp)[(size_t)row * ldo + col] = v;
            else if (out_pk) ((unsigned short*)outp)[pkaddr(row, col, ldo)] = f2bf(v);
            else ((unsigned short*)outp)[(size_t)row * ldo + col] = f2bf(v);
          }
        }
      }
    }
  }
}

// ------ heads GEMM: C[M][32] = h2[M][512] @ Bt3[32][512]^T, fp32 out ------
__launch_bounds__(256, 3)
__global__ void gemm_heads_kernel(const unsigned short* __restrict__ A,
                                  const unsigned short* __restrict__ Bt3,
                                  float* __restrict__ P3, int M, int gx_unused) {
  __shared__ unsigned short Bs[16 * 1024];  // 16 k-tiles x [32 rows][32 shorts] = 32 KB
  __shared__ unsigned short As[2 * 4096];   // ring-2 x [128][32]
  const int tid = threadIdx.x;
  const int lane = tid & 63;
  const int w = tid >> 6;
  const int lr = lane & 15, lk = lane >> 4;
  const int sw8 = (lk ^ ((lr >> 1) & 3)) * 8;

  int nwg = gridDim.x, orig = blockIdx.x;
  int q = nwg >> 3, r = nwg & 7;
  int xcd = orig & 7, lid = orig >> 3;
  int swz = (xcd < r ? xcd * (q + 1) : r * (q + 1) + (xcd - r) * q) + lid;
  int m0 = swz * 128;

  for (int i = 0; i < 8; ++i) {
    int j = i * 256 + tid;
    int n = j >> 6, p = j & 63;
    int x = (n >> 1) & 3;
    uint4 v = *reinterpret_cast<const uint4*>(Bt3 + (size_t)n * 512 + ((p & ~3) | ((p & 3) ^ x)) * 8);
    *reinterpret_cast<uint4*>(&Bs[(p >> 2) * 1024 + n * 32 + (p & 3) * 8]) = v;
  }

  f32x4 acc[2][2];
#pragma unroll
  for (int i = 0; i < 2; ++i)
#pragma unroll
    for (int j = 0; j < 2; ++j) acc[i][j] = (f32x4)0.0f;

  const int r0 = tid >> 2;
  const int slog = ((tid & 3) ^ ((r0 >> 1) & 3)) * 8;
  const unsigned short* gA = A + (size_t)(m0 + r0) * 512 + slog;
  const size_t a64 = (size_t)64 * 512;
  unsigned short* wa = As + w * 512;

  auto STG = [&](int s, int t) {
    const unsigned short* a = gA + (size_t)t * 32;
    gl_lds16(a, wa + s * 4096);
    gl_lds16(a + a64, wa + s * 4096 + 2048);
  };

  STG(0, 0);
  __syncthreads();

  int buf = 0;
  const int nt = 16;
  for (int t = 0; t < nt; ++t) {
    if (t + 1 < nt) STG(buf ^ 1, t + 1);
    const unsigned short* as_ = As + buf * 4096;
    short8 af[2], bf[2];
#pragma unroll
    for (int i = 0; i < 2; ++i) {
      af[i] = *reinterpret_cast<const short8*>(&as_[(w * 32 + i * 16 + lr) * 32 + sw8]);
      bf[i] = *reinterpret_cast<const short8*>(&Bs[t * 1024 + (i * 16 + lr) * 32 + sw8]);
    }
#pragma unroll
    for (int i = 0; i < 2; ++i)
#pragma unroll
      for (int j = 0; j < 2; ++j)
        acc[i][j] = __builtin_amdgcn_mfma_f32_16x16x32_bf16(af[i], bf[j], acc[i][j], 0, 0, 0);
    if (t + 1 < nt) {
      asm volatile("s_waitcnt vmcnt(0) lgkmcnt(0)" ::: "memory");
      __builtin_amdgcn_s_barrier();
    }
    buf ^= 1;
  }

#pragma unroll
  for (int i = 0; i < 2; ++i) {
    int row_b = m0 + w * 32 + i * 16 + lk * 4;
#pragma unroll
    for (int j = 0; j < 2; ++j) {
      int col = j * 16 + lr;
#pragma unroll
      for (int rr = 0; rr < 4; ++rr) {
        int row = row_b + rr;
        if (row < M) P3[(size_t)row * 32 + col] = acc[i][j][rr];
      }
    }
  }
}

// ---------------- host ----------------

extern "C" void kernel_launch(void* const* d_in, const int* in_sizes, int n_in,
                              void* d_out, int out_size, void* d_ws, size_t ws_size,
                              hipStream_t stream) {
  const float* x = (const float*)d_in[0];
  const void* edge = d_in[1];
  const float* w1_rel = (const float*)d_in[2];
  const float* b1 = (const float*)d_in[3];
  const float* w1_root = (const float*)d_in[4];
  const float* w2_rel = (const float*)d_in[5];
  const float* b2 = (const float*)d_in[6];
  const float* w2_root = (const float*)d_in[7];
  const float* wmu_rel = (const float*)d_in[8];
  const float* bmu = (const float*)d_in[9];
  const float* wmu_root = (const float*)d_in[10];
  const float* wls_rel = (const float*)d_in[11];
  const float* bls = (const float*)d_in[12];
  const float* wls_root = (const float*)d_in[13];

  const int FIN = 128, H1 = 1024, H2 = 512;
  const int M = in_sizes[0] / FIN;   // 20000
  const int E = in_sizes[1] / 2;     // 160000
  const int Mpad = ((M + 127) / 128) * 128;   // 20096
  const int gy = Mpad / 128;                  // 157

  char* ws = (char*)d_ws;
  size_t off = 0;
  auto alloc = [&](size_t bytes) -> char* {
    char* p = ws + off;
    off = (off + bytes + 255) & ~(size_t)255;
    return p;
  };
  int* flag = (int*)alloc(4);
  int* deg = (int*)alloc((size_t)M * 4);
  int* cursor = (int*)alloc((size_t)M * 4);
  int* rs = (int*)alloc((size_t)(M + 1) * 4);
  float* invdeg = (float*)alloc((size_t)M * 4);
  int* cs = (int*)alloc((size_t)E * 4);
  unsigned short* A1 = (unsigned short*)alloc((size_t)Mpad * 256 * 2);   // packed K=256
  unsigned short* h1 = (unsigned short*)alloc((size_t)Mpad * 1024 * 2);  // packed K=1024
  unsigned short* P2 = (unsigned short*)alloc((size_t)Mpad * 1024 * 2);  // row-major
  unsigned short* h2 = (unsigned short*)alloc((size_t)Mpad * 512 * 2);   // row-major
  float* P3 = (float*)alloc((size_t)Mpad * 32 * 4);
  unsigned short* Bt1 = (unsigned short*)alloc((size_t)H1 * 256 * 2);    // packed
  unsigned short* Bt2 = (unsigned short*)alloc((size_t)1024 * 1024 * 2); // packed
  unsigned short* Bt3 = (unsigned short*)alloc((size_t)32 * 512 * 2);    // row-major

  // prep: zero deg/cursor + flag + all weight transposes (one launch)
  prep_kernel<<<1408, 256, 0, stream>>>(deg, cursor, M, flag,
                                        w1_rel, w1_root, w2_rel, w2_root,
                                        wmu_rel, wmu_root, wls_rel, wls_root,
                                        Bt1, Bt2, Bt3);
  detect_kernel<<<8, 256, 0, stream>>>((const long long*)edge, 2048, M, flag);
  count_kernel<<<256, 256, 0, stream>>>(edge, E, flag, deg);
  scan_kernel<<<1, 1024, 0, stream>>>(deg, rs, invdeg, M);
  fill_kernel<<<256, 256, 0, stream>>>(edge, E, flag, rs, cursor, cs);

  // Layer 1: A1 = [mean(x) | x] (packed); h1 = relu(A1 @ Bt1^T + b1) (packed out)
  agg1_kernel<<<M, 128, 0, stream>>>(x, rs, cs, invdeg, A1);
  gemm_db_kernel<<<(H1 / 128) * gy / 2, 256, 0, stream>>>(
      A1, Bt1, b1, h1, 1024, M, 256, 1, 0, 1, H1 / 128);

  // Layer 2 (commuted): P2 = h1 @ [w2_rel | w2_root] (row-major out);
  // h2 = relu(mean_agg(P2_rel) + P2_root + b2)
  gemm_db_kernel<<<(1024 / 128) * gy / 2, 256, 0, stream>>>(
      h1, Bt2, nullptr, P2, 1024, M, 1024, 0, 0, 0, 1024 / 128);
  agg2_kernel<<<(M + 1) / 2, 128, 0, stream>>>(P2, rs, cs, invdeg, b2, h2, M);

  // Heads (commuted): P3 = h2 @ [4 head mats]^T (fp32, 32 cols);
  // out = mean_agg(P3_rel) + P3_root + bias
  gemm_heads_kernel<<<gy, 256, 0, stream>>>(h2, Bt3, P3, M, 1);
  float* outmu = (float*)d_out;
  float* outls = outmu + (size_t)M * 8;
  head_agg_kernel<<<(M * 16 + 255) / 256, 256, 0, stream>>>(
      P3, rs, cs, invdeg, bmu, bls, outmu, outls, M);
}

// Round 12
// 261.886 us; speedup vs baseline: 1.0357x; 1.0357x over previous
//
#include <hip/hip_runtime.h>

typedef __attribute__((ext_vector_type(8))) short short8;
typedef __attribute__((ext_vector_type(4))) float f32x4;
typedef unsigned long long u64;

__device__ __forceinline__ unsigned short f2bf(float f) {
  union { float f; unsigned u; } v; v.f = f;
  unsigned u = v.u;
  unsigned r = (u + 0x7FFFu + ((u >> 16) & 1u)) >> 16;  // RTNE
  return (unsigned short)r;
}
__device__ __forceinline__ float bf2f(unsigned short s) {
  union { unsigned u; float f; } v; v.u = ((unsigned)s) << 16;
  return v.f;
}

// async global->LDS, 16B per lane; LDS dest = wave-uniform base + lane*16
__device__ __forceinline__ void gl_lds16(const unsigned short* g, unsigned short* l) {
  __builtin_amdgcn_global_load_lds(
      (const __attribute__((address_space(1))) void*)g,
      (__attribute__((address_space(3))) void*)l, 16, 0, 0);
}

// ---------------- prep: zeroing + x->bf16 cast + weight transposes ----------------

// transpose one 32x32 tile: dst[(rowoff+n)*ldd + coloff + k] = src[k*Nw + n]
__device__ __forceinline__ void ttile(const float* __restrict__ src, int Nw,
                                      unsigned short* __restrict__ dst, int ldd,
                                      int rowoff, int coloff,
                                      int tileIdx, int tilesN, float (*tile)[33]) {
  int tk = tileIdx / tilesN, tn = tileIdx % tilesN;
  int k0 = tk * 32, n0 = tn * 32;
  int tx = threadIdx.x & 31, ty = threadIdx.x >> 5;
#pragma unroll
  for (int s = 0; s < 4; ++s)
    tile[ty + s * 8][tx] = src[(size_t)(k0 + ty + s * 8) * Nw + n0 + tx];
  __syncthreads();
#pragma unroll
  for (int s = 0; s < 4; ++s)
    dst[(size_t)(rowoff + n0 + ty + s * 8) * ldd + coloff + k0 + tx] =
        f2bf(tile[tx][ty + s * 8]);
}

__global__ void prep_kernel(int* deg, int* cursor, int n, int* flag,
                            const float* __restrict__ x, unsigned short* __restrict__ xb,
                            int total4,
                            const float* __restrict__ w1_rel, const float* __restrict__ w1_root,
                            const float* __restrict__ w2_rel, const float* __restrict__ w2_root,
                            const float* __restrict__ wmu_rel, const float* __restrict__ wmu_root,
                            const float* __restrict__ wls_rel, const float* __restrict__ wls_root,
                            unsigned short* __restrict__ Bt1,
                            unsigned short* __restrict__ Bt2,
                            unsigned short* __restrict__ Bt3) {
  __shared__ float tile[32][33];
  int b = blockIdx.x;
  if (b >= 1408) {  // 640 cast blocks: x (fp32) -> xb (bf16), float4-wide
    int b4 = (b - 1408) * 1024;
#pragma unroll
    for (int s = 0; s < 4; ++s) {
      int i4 = b4 + s * 256 + threadIdx.x;
      if (i4 < total4) {
        float4 v = reinterpret_cast<const float4*>(x)[i4];
        ushort4 o;
        o.x = f2bf(v.x); o.y = f2bf(v.y); o.z = f2bf(v.z); o.w = f2bf(v.w);
        reinterpret_cast<ushort4*>(xb)[i4] = o;
      }
    }
    return;
  }
  if (b >= 1344) {  // 64 init blocks
    int i = (b - 1344) * blockDim.x + threadIdx.x;
    int stride = 64 * blockDim.x;
    for (int j = i; j < n; j += stride) { deg[j] = 0; cursor[j] = 0; }
    if (i == 0) *flag = 1;
    return;
  }
  if (b < 128)       ttile(w1_rel, 1024, Bt1, 256, 0, 0, b, 32, tile);
  else if (b < 256)  ttile(w1_root, 1024, Bt1, 256, 0, 128, b - 128, 32, tile);
  else if (b < 768)  ttile(w2_rel, 512, Bt2, 1024, 0, 0, b - 256, 16, tile);
  else if (b < 1280) ttile(w2_root, 512, Bt2, 1024, 512, 0, b - 768, 16, tile);
  else {
    int idx = (b - 1280) * 256 + threadIdx.x;  // 64 blocks * 256 = 16384 = 32*512
    int nn = idx >> 9, k = idx & 511;
    float v;
    if (nn < 8) v = wmu_rel[(size_t)k * 8 + nn];
    else if (nn < 16) v = wmu_root[(size_t)k * 8 + (nn - 8)];
    else if (nn < 24) v = wls_rel[(size_t)k * 8 + (nn - 16)];
    else v = wls_root[(size_t)k * 8 + (nn - 24)];
    Bt3[(size_t)nn * 512 + k] = f2bf(v);
  }
}

// Detect whether edge buffer is int64 (values all in [0,n)) or int32.
__global__ void detect_kernel(const long long* p, int nslots, int n_nodes, int* flag) {
  int i = blockIdx.x * blockDim.x + threadIdx.x;
  if (i < nslots) {
    long long v = p[i];
    if (v < 0 || v >= n_nodes) atomicAnd(flag, 0);
  }
}

__device__ __forceinline__ int edge_at(const void* p, int is64, size_t idx) {
  return is64 ? (int)((const long long*)p)[idx] : ((const int*)p)[idx];
}

__global__ void count_kernel(const void* edges, int E, const int* flag, int* deg) {
  int is64 = *flag;
  int i = blockIdx.x * blockDim.x + threadIdx.x;
  int stride = gridDim.x * blockDim.x;
  for (int e = i; e < E; e += stride) {
    int d = edge_at(edges, is64, (size_t)E + e);
    atomicAdd(&deg[d], 1);
  }
}

__global__ void scan_kernel(const int* __restrict__ deg, int* __restrict__ rs,
                            float* __restrict__ invdeg, int n) {
  __shared__ int ssum[1024];
  int tid = threadIdx.x;
  int chunk = (n + 1023) >> 10;
  int start = tid * chunk;
  int end = min(start + chunk, n);
  int s = 0;
  for (int i = start; i < end; ++i) s += deg[i];
  ssum[tid] = s;
  __syncthreads();
  for (int off = 1; off < 1024; off <<= 1) {
    int t = (tid >= off) ? ssum[tid - off] : 0;
    __syncthreads();
    ssum[tid] += t;
    __syncthreads();
  }
  int run = (tid ? ssum[tid - 1] : 0);
  if (tid == 0) rs[0] = 0;
  for (int i = start; i < end; ++i) {
    int d = deg[i];
    run += d;
    rs[i + 1] = run;
    invdeg[i] = 1.0f / fmaxf((float)d, 1.0f);
  }
}

__global__ void fill_kernel(const void* edges, int E, const int* flag,
                            const int* __restrict__ rs, int* cursor, int* col_src) {
  int is64 = *flag;
  int i = blockIdx.x * blockDim.x + threadIdx.x;
  int stride = gridDim.x * blockDim.x;
  for (int e = i; e < E; e += stride) {
    int d = edge_at(edges, is64, (size_t)E + e);
    int s = edge_at(edges, is64, (size_t)e);
    int p = atomicAdd(&cursor[d], 1);
    col_src[rs[d] + p] = s;
  }
}

// ---------------- aggregation ----------------

// layer-1: A1[node] = [mean_j xb_j | xb_node], bf16 gather (4 nodes/block)
__global__ void agg1_kernel(const unsigned short* __restrict__ xb,
                            const int* __restrict__ rs, const int* __restrict__ cs,
                            const float* __restrict__ invdeg,
                            unsigned short* __restrict__ A1, int M) {
  int node = blockIdx.x * 4 + (threadIdx.x >> 6);
  if (node >= M) return;
  int c0 = (threadIdx.x & 63) * 2;
  float a0 = 0.f, a1 = 0.f;
  int e1 = rs[node + 1];
  for (int e = rs[node]; e < e1; ++e) {
    unsigned w = *reinterpret_cast<const unsigned*>(xb + (size_t)cs[e] * 128 + c0);
    a0 += bf2f((unsigned short)(w & 0xffff));
    a1 += bf2f((unsigned short)(w >> 16));
  }
  float inv = invdeg[node];
  unsigned root = *reinterpret_cast<const unsigned*>(xb + (size_t)node * 128 + c0);
  unsigned mean = (unsigned)f2bf(a0 * inv) | ((unsigned)f2bf(a1 * inv) << 16);
  *reinterpret_cast<unsigned*>(A1 + (size_t)node * 256 + c0) = mean;
  *reinterpret_cast<unsigned*>(A1 + (size_t)node * 256 + 128 + c0) = root;
}

// layer-2 combine, 2 nodes/block, 16B per lane:
// h2[i][c] = relu( inv*sum_j P2[j][c] + P2[i][512+c] + b2[c] )
__global__ void agg2_kernel(const unsigned short* __restrict__ P2,
                            const int* __restrict__ rs, const int* __restrict__ cs,
                            const float* __restrict__ invdeg,
                            const float* __restrict__ b2,
                            unsigned short* __restrict__ h2, int M) {
  int node = blockIdx.x * 2 + (threadIdx.x >> 6);
  if (node >= M) return;
  int f0 = (threadIdx.x & 63) * 8;  // 64 lanes x 8 cols = 512
  float acc[8];
#pragma unroll
  for (int v = 0; v < 8; ++v) acc[v] = 0.f;
  int e1 = rs[node + 1];
  for (int e = rs[node]; e < e1; ++e) {
    int s = cs[e];
    uint4 w = *reinterpret_cast<const uint4*>(P2 + (size_t)s * 1024 + f0);
    acc[0] += bf2f((unsigned short)(w.x & 0xffff));
    acc[1] += bf2f((unsigned short)(w.x >> 16));
    acc[2] += bf2f((unsigned short)(w.y & 0xffff));
    acc[3] += bf2f((unsigned short)(w.y >> 16));
    acc[4] += bf2f((unsigned short)(w.z & 0xffff));
    acc[5] += bf2f((unsigned short)(w.z >> 16));
    acc[6] += bf2f((unsigned short)(w.w & 0xffff));
    acc[7] += bf2f((unsigned short)(w.w >> 16));
  }
  float inv = invdeg[node];
  uint4 wr = *reinterpret_cast<const uint4*>(P2 + (size_t)node * 1024 + 512 + f0);
  float rt[8] = {
    bf2f((unsigned short)(wr.x & 0xffff)), bf2f((unsigned short)(wr.x >> 16)),
    bf2f((unsigned short)(wr.y & 0xffff)), bf2f((unsigned short)(wr.y >> 16)),
    bf2f((unsigned short)(wr.z & 0xffff)), bf2f((unsigned short)(wr.z >> 16)),
    bf2f((unsigned short)(wr.w & 0xffff)), bf2f((unsigned short)(wr.w >> 16))};
  unsigned short o[8];
#pragma unroll
  for (int v = 0; v < 8; ++v)
    o[v] = f2bf(fmaxf(acc[v] * inv + rt[v] + b2[f0 + v], 0.f));
  uint4 pk;
  pk.x = (unsigned)o[0] | ((unsigned)o[1] << 16);
  pk.y = (unsigned)o[2] | ((unsigned)o[3] << 16);
  pk.z = (unsigned)o[4] | ((unsigned)o[5] << 16);
  pk.w = (unsigned)o[6] | ((unsigned)o[7] << 16);
  *reinterpret_cast<uint4*>(h2 + (size_t)node * 512 + f0) = pk;
}

// heads combine: P3 [Mpad][32] f32: cols 0-7 mu_rel, 8-15 mu_root, 16-23 ls_rel, 24-31 ls_root
__global__ void head_agg_kernel(const float* __restrict__ P3,
                                const int* __restrict__ rs, const int* __restrict__ cs,
                                const float* __restrict__ invdeg,
                                const float* __restrict__ bmu, const float* __restrict__ bls,
                                float* __restrict__ outmu, float* __restrict__ outls, int M) {
  int idx = blockIdx.x * blockDim.x + threadIdx.x;
  int node = idx >> 4;
  int c = idx & 15;
  if (node >= M) return;
  int relc = (c < 8) ? c : (16 + (c - 8));
  float acc = 0.f;
  int e1 = rs[node + 1];
  for (int e = rs[node]; e < e1; ++e) acc += P3[(size_t)cs[e] * 32 + relc];
  float v = acc * invdeg[node] + P3[(size_t)node * 32 + relc + 8]
          + ((c < 8) ? bmu[c] : bls[c - 8]);
  if (c < 8) outmu[(size_t)node * 8 + c] = v;
  else outls[(size_t)node * 8 + (c - 8)] = v;
}

// ------ 128x128 GEMM, 4 waves, ring-2, __syncthreads per step, swizzled ------
// C[M][N] = A[M][K] * Bt[N][K]^T (+bias)(relu). BK=32. Row-major operands.
// LDS 32 KB -> 4 blocks/CU at launch_bounds(256,4). Stage(t+1) before
// compute(t); one __syncthreads per K-step (drains vm+lgkm).
// Both-sides slot-XOR swizzle (verified conflict-free, R6/R9).
__launch_bounds__(256, 4)
__global__ void gemm_db_kernel(const unsigned short* __restrict__ A, int lda,
                               const unsigned short* __restrict__ Bt, int ldb,
                               const float* __restrict__ bias,
                               void* __restrict__ outp, int ldo,
                               int M, int N, int K, int relu, int out_f32, int gx) {
  __shared__ unsigned short As[2 * 4096];
  __shared__ unsigned short Bs[2 * 4096];
  const int tid = threadIdx.x;
  const int lane = tid & 63;
  const int w = tid >> 6;
  const int wr = w >> 1, wc = w & 1;
  const int lr = lane & 15, lk = lane >> 4;
  const int sw8 = (lk ^ ((lr >> 1) & 3)) * 8;

  // bijective XCD swizzle (m204)
  int nwg = gridDim.x, orig = blockIdx.x;
  int q = nwg >> 3, r = nwg & 7;
  int xcd = orig & 7, lid = orig >> 3;
  int swz = (xcd < r ? xcd * (q + 1) : r * (q + 1) + (xcd - r) * q) + lid;
  int m0 = (swz / gx) * 128, n0 = (swz % gx) * 128;

  f32x4 acc[4][4];
#pragma unroll
  for (int i = 0; i < 4; ++i)
#pragma unroll
    for (int j = 0; j < 4; ++j) acc[i][j] = (f32x4)0.0f;

  const int r0 = tid >> 2;
  const int slog = ((tid & 3) ^ ((r0 >> 1) & 3)) * 8;
  const unsigned short* gA = A + (size_t)(m0 + r0) * lda + slog;
  const unsigned short* gB = Bt + (size_t)(n0 + r0) * ldb + slog;
  const size_t a64 = (size_t)64 * lda, b64 = (size_t)64 * ldb;
  unsigned short* wa = As + w * 512;
  unsigned short* wb = Bs + w * 512;

  auto STG = [&](int s, int t) {
    const unsigned short* a = gA + (size_t)t * 32;
    const unsigned short* b = gB + (size_t)t * 32;
    gl_lds16(a, wa + s * 4096);
    gl_lds16(a + a64, wa + s * 4096 + 2048);
    gl_lds16(b, wb + s * 4096);
    gl_lds16(b + b64, wb + s * 4096 + 2048);
  };

  const int nt = K >> 5;
  STG(0, 0);
  __syncthreads();

  int buf = 0;
  for (int t = 0; t < nt; ++t) {
    if (t + 1 < nt) STG(buf ^ 1, t + 1);
    const unsigned short* as_ = As + buf * 4096;
    const unsigned short* bs_ = Bs + buf * 4096;
    short8 af[4], bf[4];
#pragma unroll
    for (int i = 0; i < 4; ++i) {
      af[i] = *reinterpret_cast<const short8*>(&as_[(wr * 64 + i * 16 + lr) * 32 + sw8]);
      bf[i] = *reinterpret_cast<const short8*>(&bs_[(wc * 64 + i * 16 + lr) * 32 + sw8]);
    }
    __builtin_amdgcn_s_setprio(1);
#pragma unroll
    for (int i = 0; i < 4; ++i)
#pragma unroll
      for (int j = 0; j < 4; ++j)
        acc[i][j] = __builtin_amdgcn_mfma_f32_16x16x32_bf16(af[i], bf[j], acc[i][j], 0, 0, 0);
    __builtin_amdgcn_s_setprio(0);
    if (t + 1 < nt) __syncthreads();
    buf ^= 1;
  }

#pragma unroll
  for (int i = 0; i < 4; ++i) {
    int row_b = m0 + wr * 64 + i * 16 + lk * 4;
#pragma unroll
    for (int j = 0; j < 4; ++j) {
      int col = n0 + wc * 64 + j * 16 + lr;
      float bv = bias ? bias[col] : 0.f;
#pragma unroll
      for (int rr = 0; rr < 4; ++rr) {
        int row = row_b + rr;
        if (row < M) {
          float v = acc[i][j][rr] + bv;
          if (relu) v = fmaxf(v, 0.f);
          if (out_f32) ((float*)outp)[(size_t)row * ldo + col] = v;
          else ((unsigned short*)outp)[(size_t)row * ldo + col] = f2bf(v);
        }
      }
    }
  }
}

// ------ heads GEMM: C[M][32] = h2[M][512] @ Bt3[32][512]^T, fp32 out ------
__launch_bounds__(256, 3)
__global__ void gemm_heads_kernel(const unsigned short* __restrict__ A,
                                  const unsigned short* __restrict__ Bt3,
                                  float* __restrict__ P3, int M) {
  __shared__ unsigned short Bs[16 * 1024];  // 16 k-tiles x [32 rows][32 shorts] = 32 KB
  __shared__ unsigned short As[2 * 4096];   // ring-2 x [128][32]
  const int tid = threadIdx.x;
  const int lane = tid & 63;
  const int w = tid >> 6;
  const int lr = lane & 15, lk = lane >> 4;
  const int sw8 = (lk ^ ((lr >> 1) & 3)) * 8;

  int nwg = gridDim.x, orig = blockIdx.x;
  int q = nwg >> 3, r = nwg & 7;
  int xcd = orig & 7, lid = orig >> 3;
  int swz = (xcd < r ? xcd * (q + 1) : r * (q + 1) + (xcd - r) * q) + lid;
  int m0 = swz * 128;

  for (int i = 0; i < 8; ++i) {
    int j = i * 256 + tid;
    int n = j >> 6, p = j & 63;
    int x = (n >> 1) & 3;
    uint4 v = *reinterpret_cast<const uint4*>(Bt3 + (size_t)n * 512 + ((p & ~3) | ((p & 3) ^ x)) * 8);
    *reinterpret_cast<uint4*>(&Bs[(p >> 2) * 1024 + n * 32 + (p & 3) * 8]) = v;
  }

  f32x4 acc[2][2];
#pragma unroll
  for (int i = 0; i < 2; ++i)
#pragma unroll
    for (int j = 0; j < 2; ++j) acc[i][j] = (f32x4)0.0f;

  const int r0 = tid >> 2;
  const int slog = ((tid & 3) ^ ((r0 >> 1) & 3)) * 8;
  const unsigned short* gA = A + (size_t)(m0 + r0) * 512 + slog;
  const size_t a64 = (size_t)64 * 512;
  unsigned short* wa = As + w * 512;

  auto STG = [&](int s, int t) {
    const unsigned short* a = gA + (size_t)t * 32;
    gl_lds16(a, wa + s * 4096);
    gl_lds16(a + a64, wa + s * 4096 + 2048);
  };

  STG(0, 0);
  __syncthreads();

  int buf = 0;
  const int nt = 16;
  for (int t = 0; t < nt; ++t) {
    if (t + 1 < nt) STG(buf ^ 1, t + 1);
    const unsigned short* as_ = As + buf * 4096;
    short8 af[2], bf[2];
#pragma unroll
    for (int i = 0; i < 2; ++i) {
      af[i] = *reinterpret_cast<const short8*>(&as_[(w * 32 + i * 16 + lr) * 32 + sw8]);
      bf[i] = *reinterpret_cast<const short8*>(&Bs[t * 1024 + (i * 16 + lr) * 32 + sw8]);
    }
#pragma unroll
    for (int i = 0; i < 2; ++i)
#pragma unroll
      for (int j = 0; j < 2; ++j)
        acc[i][j] = __builtin_amdgcn_mfma_f32_16x16x32_bf16(af[i], bf[j], acc[i][j], 0, 0, 0);
    if (t + 1 < nt) __syncthreads();
    buf ^= 1;
  }

#pragma unroll
  for (int i = 0; i < 2; ++i) {
    int row_b = m0 + w * 32 + i * 16 + lk * 4;
#pragma unroll
    for (int j = 0; j < 2; ++j) {
      int col = j * 16 + lr;
#pragma unroll
      for (int rr = 0; rr < 4; ++rr) {
        int row = row_b + rr;
        if (row < M) P3[(size_t)row * 32 + col] = acc[i][j][rr];
      }
    }
  }
}

// ---------------- host ----------------

extern "C" void kernel_launch(void* const* d_in, const int* in_sizes, int n_in,
                              void* d_out, int out_size, void* d_ws, size_t ws_size,
                              hipStream_t stream) {
  const float* x = (const float*)d_in[0];
  const void* edge = d_in[1];
  const float* w1_rel = (const float*)d_in[2];
  const float* b1 = (const float*)d_in[3];
  const float* w1_root = (const float*)d_in[4];
  const float* w2_rel = (const float*)d_in[5];
  const float* b2 = (const float*)d_in[6];
  const float* w2_root = (const float*)d_in[7];
  const float* wmu_rel = (const float*)d_in[8];
  const float* bmu = (const float*)d_in[9];
  const float* wmu_root = (const float*)d_in[10];
  const float* wls_rel = (const float*)d_in[11];
  const float* bls = (const float*)d_in[12];
  const float* wls_root = (const float*)d_in[13];

  const int FIN = 128, H1 = 1024, H2 = 512;
  const int M = in_sizes[0] / FIN;   // 20000
  const int E = in_sizes[1] / 2;     // 160000
  const int Mpad = ((M + 127) / 128) * 128;   // 20096
  const int gy = Mpad / 128;                  // 157

  char* ws = (char*)d_ws;
  size_t off = 0;
  auto alloc = [&](size_t bytes) -> char* {
    char* p = ws + off;
    off = (off + bytes + 255) & ~(size_t)255;
    return p;
  };
  int* flag = (int*)alloc(4);
  int* deg = (int*)alloc((size_t)M * 4);
  int* cursor = (int*)alloc((size_t)M * 4);
  int* rs = (int*)alloc((size_t)(M + 1) * 4);
  float* invdeg = (float*)alloc((size_t)M * 4);
  int* cs = (int*)alloc((size_t)E * 4);
  unsigned short* xb = (unsigned short*)alloc((size_t)M * 128 * 2);      // bf16 x
  unsigned short* A1 = (unsigned short*)alloc((size_t)Mpad * 256 * 2);   // [mean|x]
  unsigned short* h1 = (unsigned short*)alloc((size_t)Mpad * 1024 * 2);
  unsigned short* P2 = (unsigned short*)alloc((size_t)Mpad * 1024 * 2);
  unsigned short* h2 = (unsigned short*)alloc((size_t)Mpad * 512 * 2);
  float* P3 = (float*)alloc((size_t)Mpad * 32 * 4);
  unsigned short* Bt1 = (unsigned short*)alloc((size_t)H1 * 256 * 2);
  unsigned short* Bt2 = (unsigned short*)alloc((size_t)1024 * 1024 * 2);
  unsigned short* Bt3 = (unsigned short*)alloc((size_t)32 * 512 * 2);

  // prep: zero deg/cursor + flag + x->bf16 + all weight transposes (one launch)
  prep_kernel<<<2048, 256, 0, stream>>>(deg, cursor, M, flag,
                                        x, xb, M * FIN / 4,
                                        w1_rel, w1_root, w2_rel, w2_root,
                                        wmu_rel, wmu_root, wls_rel, wls_root,
                                        Bt1, Bt2, Bt3);
  detect_kernel<<<8, 256, 0, stream>>>((const long long*)edge, 2048, M, flag);
  count_kernel<<<256, 256, 0, stream>>>(edge, E, flag, deg);
  scan_kernel<<<1, 1024, 0, stream>>>(deg, rs, invdeg, M);
  fill_kernel<<<256, 256, 0, stream>>>(edge, E, flag, rs, cursor, cs);

  // Layer 1: A1 = [mean(xb) | xb]; h1 = relu(A1 @ Bt1^T + b1)
  agg1_kernel<<<(M + 3) / 4, 256, 0, stream>>>(xb, rs, cs, invdeg, A1, M);
  gemm_db_kernel<<<(H1 / 128) * gy, 256, 0, stream>>>(
      A1, 256, Bt1, 256, b1, h1, 1024, M, H1, 256, 1, 0, H1 / 128);

  // Layer 2 (commuted): P2 = h1 @ [w2_rel | w2_root]; h2 = relu(mean_agg(P2_rel) + P2_root + b2)
  gemm_db_kernel<<<(1024 / 128) * gy, 256, 0, stream>>>(
      h1, 1024, Bt2, 1024, nullptr, P2, 1024, M, 1024, 1024, 0, 0, 1024 / 128);
  agg2_kernel<<<(M + 1) / 2, 128, 0, stream>>>(P2, rs, cs, invdeg, b2, h2, M);

  // Heads (commuted): P3 = h2 @ [4 head mats]^T (fp32, 32 cols);
  // out = mean_agg(P3_rel) + P3_root + bias
  gemm_heads_kernel<<<gy, 256, 0, stream>>>(h2, Bt3, P3, M);
  float* outmu = (float*)d_out;
  float* outls = outmu + (size_t)M * 8;
  head_agg_kernel<<<(M * 16 + 255) / 256, 256, 0, stream>>>(
      P3, rs, cs, invdeg, bmu, bls, outmu, outls, M);
}

// Round 13
// 249.558 us; speedup vs baseline: 1.0869x; 1.0494x over previous
//
#include <hip/hip_runtime.h>

typedef __attribute__((ext_vector_type(8))) short short8;
typedef __attribute__((ext_vector_type(4))) float f32x4;
typedef unsigned long long u64;

__device__ __forceinline__ unsigned short f2bf(float f) {
  union { float f; unsigned u; } v; v.f = f;
  unsigned u = v.u;
  unsigned r = (u + 0x7FFFu + ((u >> 16) & 1u)) >> 16;  // RTNE
  return (unsigned short)r;
}
__device__ __forceinline__ float bf2f(unsigned short s) {
  union { unsigned u; float f; } v; v.u = ((unsigned)s) << 16;
  return v.f;
}

// async global->LDS, 16B per lane; LDS dest = wave-uniform base + lane*16
__device__ __forceinline__ void gl_lds16(const unsigned short* g, unsigned short* l) {
  __builtin_amdgcn_global_load_lds(
      (const __attribute__((address_space(1))) void*)g,
      (__attribute__((address_space(3))) void*)l, 16, 0, 0);
}

// int64-vs-int32 edge dtype detection, pure function (no flag kernel):
// int32 data in [0,2e4) interpreted as int64 pairs has hi!=0 w.p. 1-1/20000
// per slot; 8 slots -> misdetection P ~ (1/2e4)^8 ~ 4e-35.
__device__ __forceinline__ int detect64(const void* edges, int n_nodes) {
  const long long* p = (const long long*)edges;
  int ok = 1;
#pragma unroll
  for (int i = 0; i < 8; ++i) {
    long long v = p[i];
    if (v < 0 || v >= n_nodes) ok = 0;
  }
  return ok;
}

// ---------------- prep: zeroing + x->bf16 cast + weight transposes ----------------

__device__ __forceinline__ void ttile(const float* __restrict__ src, int Nw,
                                      unsigned short* __restrict__ dst, int ldd,
                                      int rowoff, int coloff,
                                      int tileIdx, int tilesN, float (*tile)[33]) {
  int tk = tileIdx / tilesN, tn = tileIdx % tilesN;
  int k0 = tk * 32, n0 = tn * 32;
  int tx = threadIdx.x & 31, ty = threadIdx.x >> 5;
#pragma unroll
  for (int s = 0; s < 4; ++s)
    tile[ty + s * 8][tx] = src[(size_t)(k0 + ty + s * 8) * Nw + n0 + tx];
  __syncthreads();
#pragma unroll
  for (int s = 0; s < 4; ++s)
    dst[(size_t)(rowoff + n0 + ty + s * 8) * ldd + coloff + k0 + tx] =
        f2bf(tile[tx][ty + s * 8]);
}

__global__ void prep_kernel(int* deg, int* cursor, int n,
                            const float* __restrict__ x, unsigned short* __restrict__ xb,
                            int total4,
                            const float* __restrict__ w1_rel, const float* __restrict__ w1_root,
                            const float* __restrict__ w2_rel, const float* __restrict__ w2_root,
                            const float* __restrict__ wmu_rel, const float* __restrict__ wmu_root,
                            const float* __restrict__ wls_rel, const float* __restrict__ wls_root,
                            unsigned short* __restrict__ Bt1,
                            unsigned short* __restrict__ Bt2,
                            unsigned short* __restrict__ Bt3) {
  __shared__ float tile[32][33];
  int b = blockIdx.x;
  if (b >= 1408) {  // 640 cast blocks: x (fp32) -> xb (bf16), float4-wide
    int b4 = (b - 1408) * 1024;
#pragma unroll
    for (int s = 0; s < 4; ++s) {
      int i4 = b4 + s * 256 + threadIdx.x;
      if (i4 < total4) {
        float4 v = reinterpret_cast<const float4*>(x)[i4];
        ushort4 o;
        o.x = f2bf(v.x); o.y = f2bf(v.y); o.z = f2bf(v.z); o.w = f2bf(v.w);
        reinterpret_cast<ushort4*>(xb)[i4] = o;
      }
    }
    return;
  }
  if (b >= 1344) {  // 64 init blocks
    int i = (b - 1344) * blockDim.x + threadIdx.x;
    int stride = 64 * blockDim.x;
    for (int j = i; j < n; j += stride) { deg[j] = 0; cursor[j] = 0; }
    return;
  }
  if (b < 128)       ttile(w1_rel, 1024, Bt1, 256, 0, 0, b, 32, tile);
  else if (b < 256)  ttile(w1_root, 1024, Bt1, 256, 0, 128, b - 128, 32, tile);
  else if (b < 768)  ttile(w2_rel, 512, Bt2, 1024, 0, 0, b - 256, 16, tile);
  else if (b < 1280) ttile(w2_root, 512, Bt2, 1024, 512, 0, b - 768, 16, tile);
  else {
    int idx = (b - 1280) * 256 + threadIdx.x;  // 64 blocks * 256 = 16384 = 32*512
    int nn = idx >> 9, k = idx & 511;
    float v;
    if (nn < 8) v = wmu_rel[(size_t)k * 8 + nn];
    else if (nn < 16) v = wmu_root[(size_t)k * 8 + (nn - 8)];
    else if (nn < 24) v = wls_rel[(size_t)k * 8 + (nn - 16)];
    else v = wls_root[(size_t)k * 8 + (nn - 24)];
    Bt3[(size_t)nn * 512 + k] = f2bf(v);
  }
}

__device__ __forceinline__ int edge_at(const void* p, int is64, size_t idx) {
  return is64 ? (int)((const long long*)p)[idx] : ((const int*)p)[idx];
}

__global__ void count_kernel(const void* edges, int E, int n_nodes, int* deg) {
  int is64 = detect64(edges, n_nodes);
  int i = blockIdx.x * blockDim.x + threadIdx.x;
  int stride = gridDim.x * blockDim.x;
  for (int e = i; e < E; e += stride) {
    int d = edge_at(edges, is64, (size_t)E + e);
    atomicAdd(&deg[d], 1);
  }
}

__global__ void scan_kernel(const int* __restrict__ deg, int* __restrict__ rs,
                            float* __restrict__ invdeg, int n) {
  __shared__ int ssum[1024];
  int tid = threadIdx.x;
  int chunk = (n + 1023) >> 10;
  int start = tid * chunk;
  int end = min(start + chunk, n);
  int s = 0;
  for (int i = start; i < end; ++i) s += deg[i];
  ssum[tid] = s;
  __syncthreads();
  for (int off = 1; off < 1024; off <<= 1) {
    int t = (tid >= off) ? ssum[tid - off] : 0;
    __syncthreads();
    ssum[tid] += t;
    __syncthreads();
  }
  int run = (tid ? ssum[tid - 1] : 0);
  if (tid == 0) rs[0] = 0;
  for (int i = start; i < end; ++i) {
    int d = deg[i];
    run += d;
    rs[i + 1] = run;
    invdeg[i] = 1.0f / fmaxf((float)d, 1.0f);
  }
}

__global__ void fill_kernel(const void* edges, int E, int n_nodes,
                            const int* __restrict__ rs, int* cursor, int* col_src) {
  int is64 = detect64(edges, n_nodes);
  int i = blockIdx.x * blockDim.x + threadIdx.x;
  int stride = gridDim.x * blockDim.x;
  for (int e = i; e < E; e += stride) {
    int d = edge_at(edges, is64, (size_t)E + e);
    int s = edge_at(edges, is64, (size_t)e);
    int p = atomicAdd(&cursor[d], 1);
    col_src[rs[d] + p] = s;
  }
}

// ---------------- aggregation ----------------

// layer-1: A1[node] = [mean_j xb_j | xb_node], bf16 gather (4 nodes/block)
__global__ void agg1_kernel(const unsigned short* __restrict__ xb,
                            const int* __restrict__ rs, const int* __restrict__ cs,
                            const float* __restrict__ invdeg,
                            unsigned short* __restrict__ A1, int M) {
  int node = blockIdx.x * 4 + (threadIdx.x >> 6);
  if (node >= M) return;
  int c0 = (threadIdx.x & 63) * 2;
  float a0 = 0.f, a1 = 0.f;
  int e1 = rs[node + 1];
  for (int e = rs[node]; e < e1; ++e) {
    unsigned w = *reinterpret_cast<const unsigned*>(xb + (size_t)cs[e] * 128 + c0);
    a0 += bf2f((unsigned short)(w & 0xffff));
    a1 += bf2f((unsigned short)(w >> 16));
  }
  float inv = invdeg[node];
  unsigned root = *reinterpret_cast<const unsigned*>(xb + (size_t)node * 128 + c0);
  unsigned mean = (unsigned)f2bf(a0 * inv) | ((unsigned)f2bf(a1 * inv) << 16);
  *reinterpret_cast<unsigned*>(A1 + (size_t)node * 256 + c0) = mean;
  *reinterpret_cast<unsigned*>(A1 + (size_t)node * 256 + 128 + c0) = root;
}

// layer-2 combine, 4 nodes/block (256 thr), 16B per lane:
// h2[i][c] = relu( inv*sum_j P2[j][c] + P2[i][512+c] + b2[c] )
__global__ void agg2_kernel(const unsigned short* __restrict__ P2,
                            const int* __restrict__ rs, const int* __restrict__ cs,
                            const float* __restrict__ invdeg,
                            const float* __restrict__ b2,
                            unsigned short* __restrict__ h2, int M) {
  int node = blockIdx.x * 4 + (threadIdx.x >> 6);
  if (node >= M) return;
  int f0 = (threadIdx.x & 63) * 8;  // 64 lanes x 8 cols = 512
  float acc[8];
#pragma unroll
  for (int v = 0; v < 8; ++v) acc[v] = 0.f;
  int e1 = rs[node + 1];
  for (int e = rs[node]; e < e1; ++e) {
    int s = cs[e];
    uint4 w = *reinterpret_cast<const uint4*>(P2 + (size_t)s * 1024 + f0);
    acc[0] += bf2f((unsigned short)(w.x & 0xffff));
    acc[1] += bf2f((unsigned short)(w.x >> 16));
    acc[2] += bf2f((unsigned short)(w.y & 0xffff));
    acc[3] += bf2f((unsigned short)(w.y >> 16));
    acc[4] += bf2f((unsigned short)(w.z & 0xffff));
    acc[5] += bf2f((unsigned short)(w.z >> 16));
    acc[6] += bf2f((unsigned short)(w.w & 0xffff));
    acc[7] += bf2f((unsigned short)(w.w >> 16));
  }
  float inv = invdeg[node];
  uint4 wr = *reinterpret_cast<const uint4*>(P2 + (size_t)node * 1024 + 512 + f0);
  float rt[8] = {
    bf2f((unsigned short)(wr.x & 0xffff)), bf2f((unsigned short)(wr.x >> 16)),
    bf2f((unsigned short)(wr.y & 0xffff)), bf2f((unsigned short)(wr.y >> 16)),
    bf2f((unsigned short)(wr.z & 0xffff)), bf2f((unsigned short)(wr.z >> 16)),
    bf2f((unsigned short)(wr.w & 0xffff)), bf2f((unsigned short)(wr.w >> 16))};
  unsigned short o[8];
#pragma unroll
  for (int v = 0; v < 8; ++v)
    o[v] = f2bf(fmaxf(acc[v] * inv + rt[v] + b2[f0 + v], 0.f));
  uint4 pk;
  pk.x = (unsigned)o[0] | ((unsigned)o[1] << 16);
  pk.y = (unsigned)o[2] | ((unsigned)o[3] << 16);
  pk.z = (unsigned)o[4] | ((unsigned)o[5] << 16);
  pk.w = (unsigned)o[6] | ((unsigned)o[7] << 16);
  *reinterpret_cast<uint4*>(h2 + (size_t)node * 512 + f0) = pk;
}

// heads combine: P3 [Mpad][32] f32: cols 0-7 mu_rel, 8-15 mu_root, 16-23 ls_rel, 24-31 ls_root
__global__ void head_agg_kernel(const float* __restrict__ P3,
                                const int* __restrict__ rs, const int* __restrict__ cs,
                                const float* __restrict__ invdeg,
                                const float* __restrict__ bmu, const float* __restrict__ bls,
                                float* __restrict__ outmu, float* __restrict__ outls, int M) {
  int idx = blockIdx.x * blockDim.x + threadIdx.x;
  int node = idx >> 4;
  int c = idx & 15;
  if (node >= M) return;
  int relc = (c < 8) ? c : (16 + (c - 8));
  float acc = 0.f;
  int e1 = rs[node + 1];
  for (int e = rs[node]; e < e1; ++e) acc += P3[(size_t)cs[e] * 32 + relc];
  float v = acc * invdeg[node] + P3[(size_t)node * 32 + relc + 8]
          + ((c < 8) ? bmu[c] : bls[c - 8]);
  if (c < 8) outmu[(size_t)node * 8 + c] = v;
  else outls[(size_t)node * 8 + (c - 8)] = v;
}

// ------ 128x128 GEMM, 4 waves, ring-2, __syncthreads per step, swizzled ------
// (R12 kernel, frozen; used for layer 1.)
__launch_bounds__(256, 4)
__global__ void gemm_db_kernel(const unsigned short* __restrict__ A, int lda,
                               const unsigned short* __restrict__ Bt, int ldb,
                               const float* __restrict__ bias,
                               void* __restrict__ outp, int ldo,
                               int M, int N, int K, int relu, int out_f32, int gx) {
  __shared__ unsigned short As[2 * 4096];
  __shared__ unsigned short Bs[2 * 4096];
  const int tid = threadIdx.x;
  const int lane = tid & 63;
  const int w = tid >> 6;
  const int wr = w >> 1, wc = w & 1;
  const int lr = lane & 15, lk = lane >> 4;
  const int sw8 = (lk ^ ((lr >> 1) & 3)) * 8;

  int nwg = gridDim.x, orig = blockIdx.x;
  int q = nwg >> 3, r = nwg & 7;
  int xcd = orig & 7, lid = orig >> 3;
  int swz = (xcd < r ? xcd * (q + 1) : r * (q + 1) + (xcd - r) * q) + lid;
  int m0 = (swz / gx) * 128, n0 = (swz % gx) * 128;

  f32x4 acc[4][4];
#pragma unroll
  for (int i = 0; i < 4; ++i)
#pragma unroll
    for (int j = 0; j < 4; ++j) acc[i][j] = (f32x4)0.0f;

  const int r0 = tid >> 2;
  const int slog = ((tid & 3) ^ ((r0 >> 1) & 3)) * 8;
  const unsigned short* gA = A + (size_t)(m0 + r0) * lda + slog;
  const unsigned short* gB = Bt + (size_t)(n0 + r0) * ldb + slog;
  const size_t a64 = (size_t)64 * lda, b64 = (size_t)64 * ldb;
  unsigned short* wa = As + w * 512;
  unsigned short* wb = Bs + w * 512;

  auto STG = [&](int s, int t) {
    const unsigned short* a = gA + (size_t)t * 32;
    const unsigned short* b = gB + (size_t)t * 32;
    gl_lds16(a, wa + s * 4096);
    gl_lds16(a + a64, wa + s * 4096 + 2048);
    gl_lds16(b, wb + s * 4096);
    gl_lds16(b + b64, wb + s * 4096 + 2048);
  };

  const int nt = K >> 5;
  STG(0, 0);
  __syncthreads();

  int buf = 0;
  for (int t = 0; t < nt; ++t) {
    if (t + 1 < nt) STG(buf ^ 1, t + 1);
    const unsigned short* as_ = As + buf * 4096;
    const unsigned short* bs_ = Bs + buf * 4096;
    short8 af[4], bf[4];
#pragma unroll
    for (int i = 0; i < 4; ++i) {
      af[i] = *reinterpret_cast<const short8*>(&as_[(wr * 64 + i * 16 + lr) * 32 + sw8]);
      bf[i] = *reinterpret_cast<const short8*>(&bs_[(wc * 64 + i * 16 + lr) * 32 + sw8]);
    }
    __builtin_amdgcn_s_setprio(1);
#pragma unroll
    for (int i = 0; i < 4; ++i)
#pragma unroll
      for (int j = 0; j < 4; ++j)
        acc[i][j] = __builtin_amdgcn_mfma_f32_16x16x32_bf16(af[i], bf[j], acc[i][j], 0, 0, 0);
    __builtin_amdgcn_s_setprio(0);
    if (t + 1 < nt) __syncthreads();
    buf ^= 1;
  }

#pragma unroll
  for (int i = 0; i < 4; ++i) {
    int row_b = m0 + wr * 64 + i * 16 + lk * 4;
#pragma unroll
    for (int j = 0; j < 4; ++j) {
      int col = n0 + wc * 64 + j * 16 + lr;
      float bv = bias ? bias[col] : 0.f;
#pragma unroll
      for (int rr = 0; rr < 4; ++rr) {
        int row = row_b + rr;
        if (row < M) {
          float v = acc[i][j][rr] + bv;
          if (relu) v = fmaxf(v, 0.f);
          if (out_f32) ((float*)outp)[(size_t)row * ldo + col] = v;
          else ((unsigned short*)outp)[(size_t)row * ldo + col] = f2bf(v);
        }
      }
    }
  }
}

// ------ barrier-free 1-wave GEMM: 64x64 tile/wave, ring-2, counted vmcnt ------
// C[M][N] = A[M][K]*Bt[N][K]^T, bf16 out. 64-thread blocks; LDS 16KB/block ->
// 10 blocks/CU. No s_barrier: wave-local {ds_read -> lgkmcnt(0) (WAR fence) ->
// stage next -> MFMA -> vmcnt}. Both-sides slot-XOR swizzle (1-wave lane map:
// stage xor term (l>>3)&3 is lane-constant; read side same involution).
__launch_bounds__(64, 2)
__global__ void gemm_wv_kernel(const unsigned short* __restrict__ A, int lda,
                               const unsigned short* __restrict__ Bt, int ldb,
                               unsigned short* __restrict__ outp, int ldo,
                               int M, int K, int gx) {
  __shared__ unsigned short As[2 * 2048];  // 2 x [64 rows][32 shorts]
  __shared__ unsigned short Bs[2 * 2048];
  const int l = threadIdx.x;
  const int lr = l & 15, lk = l >> 4;
  const int sw8 = (lk ^ ((lr >> 1) & 3)) * 8;

  // bijective XCD swizzle (m204)
  int nwg = gridDim.x, orig = blockIdx.x;
  int q = nwg >> 3, r = nwg & 7;
  int xcd = orig & 7, lid = orig >> 3;
  int swz = (xcd < r ? xcd * (q + 1) : r * (q + 1) + (xcd - r) * q) + lid;
  int m0 = (swz / gx) * 64, n0 = (swz % gx) * 64;

  f32x4 acc[4][4];
#pragma unroll
  for (int i = 0; i < 4; ++i)
#pragma unroll
    for (int j = 0; j < 4; ++j) acc[i][j] = (f32x4)0.0f;

  // staging lane map: chunk c covers rows c*16..c*16+15; lane l -> row
  // c*16+(l>>2), phys slot l&3, global slot (l&3)^((row>>1)&3) = (l&3)^((l>>3)&3)
  const int srow = l >> 2;
  const int sslot = ((l & 3) ^ ((l >> 3) & 3)) * 8;
  const unsigned short* gA = A + (size_t)(m0 + srow) * lda + sslot;
  const unsigned short* gB = Bt + (size_t)(n0 + srow) * ldb + sslot;

  auto STG = [&](int s, int t) {
#pragma unroll
    for (int c = 0; c < 4; ++c) {
      gl_lds16(gA + (size_t)t * 32 + (size_t)(c * 16) * lda, As + s * 2048 + c * 512);
      gl_lds16(gB + (size_t)t * 32 + (size_t)(c * 16) * ldb, Bs + s * 2048 + c * 512);
    }
  };

  const int nt = K >> 5;  // >= 2
  STG(0, 0);
  STG(1, 1);
  asm volatile("s_waitcnt vmcnt(8)" ::: "memory");  // tile 0 landed; tile 1 flying

  for (int t = 0; t < nt; ++t) {
    const unsigned short* as_ = As + (t & 1) * 2048;
    const unsigned short* bs_ = Bs + (t & 1) * 2048;
    short8 af[4], bf[4];
#pragma unroll
    for (int i = 0; i < 4; ++i) {
      af[i] = *reinterpret_cast<const short8*>(&as_[(i * 16 + lr) * 32 + sw8]);
      bf[i] = *reinterpret_cast<const short8*>(&bs_[(i * 16 + lr) * 32 + sw8]);
    }
    // WAR fence: fragment reads landed in VGPRs -> safe to overwrite this buffer
    asm volatile("s_waitcnt lgkmcnt(0)" ::: "memory");
    if (t + 2 < nt) STG(t & 1, t + 2);
    __builtin_amdgcn_s_setprio(1);
#pragma unroll
    for (int i = 0; i < 4; ++i)
#pragma unroll
      for (int j = 0; j < 4; ++j)
        acc[i][j] = __builtin_amdgcn_mfma_f32_16x16x32_bf16(af[i], bf[j], acc[i][j], 0, 0, 0);
    __builtin_amdgcn_s_setprio(0);
    if (t + 1 < nt) {
      if (t + 2 < nt)
        asm volatile("s_waitcnt vmcnt(8)" ::: "memory");  // t+1 landed; t+2 flying
      else
        asm volatile("s_waitcnt vmcnt(0)" ::: "memory");
    }
  }

#pragma unroll
  for (int i = 0; i < 4; ++i) {
    int row_b = m0 + i * 16 + lk * 4;
#pragma unroll
    for (int j = 0; j < 4; ++j) {
      int col = n0 + j * 16 + lr;
#pragma unroll
      for (int rr = 0; rr < 4; ++rr) {
        int row = row_b + rr;
        if (row < M) outp[(size_t)row * ldo + col] = f2bf(acc[i][j][rr]);
      }
    }
  }
}

// ------ heads GEMM: C[M][32] = h2[M][512] @ Bt3[32][512]^T, fp32 out ------
__launch_bounds__(256, 3)
__global__ void gemm_heads_kernel(const unsigned short* __restrict__ A,
                                  const unsigned short* __restrict__ Bt3,
                                  float* __restrict__ P3, int M) {
  __shared__ unsigned short Bs[16 * 1024];
  __shared__ unsigned short As[2 * 4096];
  const int tid = threadIdx.x;
  const int lane = tid & 63;
  const int w = tid >> 6;
  const int lr = lane & 15, lk = lane >> 4;
  const int sw8 = (lk ^ ((lr >> 1) & 3)) * 8;

  int nwg = gridDim.x, orig = blockIdx.x;
  int q = nwg >> 3, r = nwg & 7;
  int xcd = orig & 7, lid = orig >> 3;
  int swz = (xcd < r ? xcd * (q + 1) : r * (q + 1) + (xcd - r) * q) + lid;
  int m0 = swz * 128;

  for (int i = 0; i < 8; ++i) {
    int j = i * 256 + tid;
    int n = j >> 6, p = j & 63;
    int x = (n >> 1) & 3;
    uint4 v = *reinterpret_cast<const uint4*>(Bt3 + (size_t)n * 512 + ((p & ~3) | ((p & 3) ^ x)) * 8);
    *reinterpret_cast<uint4*>(&Bs[(p >> 2) * 1024 + n * 32 + (p & 3) * 8]) = v;
  }

  f32x4 acc[2][2];
#pragma unroll
  for (int i = 0; i < 2; ++i)
#pragma unroll
    for (int j = 0; j < 2; ++j) acc[i][j] = (f32x4)0.0f;

  const int r0 = tid >> 2;
  const int slog = ((tid & 3) ^ ((r0 >> 1) & 3)) * 8;
  const unsigned short* gA = A + (size_t)(m0 + r0) * 512 + slog;
  const size_t a64 = (size_t)64 * 512;
  unsigned short* wa = As + w * 512;

  auto STG = [&](int s, int t) {
    const unsigned short* a = gA + (size_t)t * 32;
    gl_lds16(a, wa + s * 4096);
    gl_lds16(a + a64, wa + s * 4096 + 2048);
  };

  STG(0, 0);
  __syncthreads();

  int buf = 0;
  const int nt = 16;
  for (int t = 0; t < nt; ++t) {
    if (t + 1 < nt) STG(buf ^ 1, t + 1);
    const unsigned short* as_ = As + buf * 4096;
    short8 af[2], bf[2];
#pragma unroll
    for (int i = 0; i < 2; ++i) {
      af[i] = *reinterpret_cast<const short8*>(&as_[(w * 32 + i * 16 + lr) * 32 + sw8]);
      bf[i] = *reinterpret_cast<const short8*>(&Bs[t * 1024 + (i * 16 + lr) * 32 + sw8]);
    }
#pragma unroll
    for (int i = 0; i < 2; ++i)
#pragma unroll
      for (int j = 0; j < 2; ++j)
        acc[i][j] = __builtin_amdgcn_mfma_f32_16x16x32_bf16(af[i], bf[j], acc[i][j], 0, 0, 0);
    if (t + 1 < nt) __syncthreads();
    buf ^= 1;
  }

#pragma unroll
  for (int i = 0; i < 2; ++i) {
    int row_b = m0 + w * 32 + i * 16 + lk * 4;
#pragma unroll
    for (int j = 0; j < 2; ++j) {
      int col = j * 16 + lr;
#pragma unroll
      for (int rr = 0; rr < 4; ++rr) {
        int row = row_b + rr;
        if (row < M) P3[(size_t)row * 32 + col] = acc[i][j][rr];
      }
    }
  }
}

// ---------------- host ----------------

extern "C" void kernel_launch(void* const* d_in, const int* in_sizes, int n_in,
                              void* d_out, int out_size, void* d_ws, size_t ws_size,
                              hipStream_t stream) {
  const float* x = (const float*)d_in[0];
  const void* edge = d_in[1];
  const float* w1_rel = (const float*)d_in[2];
  const float* b1 = (const float*)d_in[3];
  const float* w1_root = (const float*)d_in[4];
  const float* w2_rel = (const float*)d_in[5];
  const float* b2 = (const float*)d_in[6];
  const float* w2_root = (const float*)d_in[7];
  const float* wmu_rel = (const float*)d_in[8];
  const float* bmu = (const float*)d_in[9];
  const float* wmu_root = (const float*)d_in[10];
  const float* wls_rel = (const float*)d_in[11];
  const float* bls = (const float*)d_in[12];
  const float* wls_root = (const float*)d_in[13];

  const int FIN = 128, H1 = 1024, H2 = 512;
  const int M = in_sizes[0] / FIN;   // 20000
  const int E = in_sizes[1] / 2;     // 160000
  const int Mpad = ((M + 127) / 128) * 128;   // 20096
  const int gy = Mpad / 128;                  // 157
  const int gy64 = Mpad / 64;                 // 314

  char* ws = (char*)d_ws;
  size_t off = 0;
  auto alloc = [&](size_t bytes) -> char* {
    char* p = ws + off;
    off = (off + bytes + 255) & ~(size_t)255;
    return p;
  };
  int* deg = (int*)alloc((size_t)M * 4);
  int* cursor = (int*)alloc((size_t)M * 4);
  int* rs = (int*)alloc((size_t)(M + 1) * 4);
  float* invdeg = (float*)alloc((size_t)M * 4);
  int* cs = (int*)alloc((size_t)E * 4);
  unsigned short* xb = (unsigned short*)alloc((size_t)M * 128 * 2);
  unsigned short* A1 = (unsigned short*)alloc((size_t)Mpad * 256 * 2);
  unsigned short* h1 = (unsigned short*)alloc((size_t)Mpad * 1024 * 2);
  unsigned short* P2 = (unsigned short*)alloc((size_t)Mpad * 1024 * 2);
  unsigned short* h2 = (unsigned short*)alloc((size_t)Mpad * 512 * 2);
  float* P3 = (float*)alloc((size_t)Mpad * 32 * 4);
  unsigned short* Bt1 = (unsigned short*)alloc((size_t)H1 * 256 * 2);
  unsigned short* Bt2 = (unsigned short*)alloc((size_t)1024 * 1024 * 2);
  unsigned short* Bt3 = (unsigned short*)alloc((size_t)32 * 512 * 2);

  // prep: zero deg/cursor + x->bf16 + all weight transposes (one launch)
  prep_kernel<<<2048, 256, 0, stream>>>(deg, cursor, M,
                                        x, xb, M * FIN / 4,
                                        w1_rel, w1_root, w2_rel, w2_root,
                                        wmu_rel, wmu_root, wls_rel, wls_root,
                                        Bt1, Bt2, Bt3);
  count_kernel<<<256, 256, 0, stream>>>(edge, E, M, deg);
  scan_kernel<<<1, 1024, 0, stream>>>(deg, rs, invdeg, M);
  fill_kernel<<<256, 256, 0, stream>>>(edge, E, M, rs, cursor, cs);

  // Layer 1: A1 = [mean(xb) | xb]; h1 = relu(A1 @ Bt1^T + b1)
  agg1_kernel<<<(M + 3) / 4, 256, 0, stream>>>(xb, rs, cs, invdeg, A1, M);
  gemm_db_kernel<<<(H1 / 128) * gy, 256, 0, stream>>>(
      A1, 256, Bt1, 256, b1, h1, 1024, M, H1, 256, 1, 0, H1 / 128);

  // Layer 2 (commuted): P2 = h1 @ [w2_rel | w2_root]  (barrier-free wave GEMM)
  gemm_wv_kernel<<<(1024 / 64) * gy64, 64, 0, stream>>>(
      h1, 1024, Bt2, 1024, P2, 1024, M, 1024, 1024 / 64);
  agg2_kernel<<<(M + 3) / 4, 256, 0, stream>>>(P2, rs, cs, invdeg, b2, h2, M);

  // Heads (commuted): P3 = h2 @ [4 head mats]^T; out = mean_agg(P3_rel) + P3_root + bias
  gemm_heads_kernel<<<gy, 256, 0, stream>>>(h2, Bt3, P3, M);
  float* outmu = (float*)d_out;
  float* outls = outmu + (size_t)M * 8;
  head_agg_kernel<<<(M * 16 + 255) / 256, 256, 0, stream>>>(
      P3, rs, cs, invdeg, bmu, bls, outmu, outls, M);
}

// Round 14
// 236.350 us; speedup vs baseline: 1.1476x; 1.0559x over previous
//
#include <hip/hip_runtime.h>

typedef __attribute__((ext_vector_type(8))) short short8;
typedef __attribute__((ext_vector_type(4))) float f32x4;
typedef unsigned long long u64;

__device__ __forceinline__ unsigned short f2bf(float f) {
  union { float f; unsigned u; } v; v.f = f;
  unsigned u = v.u;
  unsigned r = (u + 0x7FFFu + ((u >> 16) & 1u)) >> 16;  // RTNE
  return (unsigned short)r;
}
__device__ __forceinline__ float bf2f(unsigned short s) {
  union { unsigned u; float f; } v; v.u = ((unsigned)s) << 16;
  return v.f;
}

// async global->LDS, 16B per lane; LDS dest = wave-uniform base + lane*16
__device__ __forceinline__ void gl_lds16(const unsigned short* g, unsigned short* l) {
  __builtin_amdgcn_global_load_lds(
      (const __attribute__((address_space(1))) void*)g,
      (__attribute__((address_space(3))) void*)l, 16, 0, 0);
}

// int64-vs-int32 edge dtype detection, pure function:
// int32 pairs reinterpreted as int64 land outside [0,n) w.h.p.;
// 8 slots -> misdetection P ~ (1/2e4)^8.
__device__ __forceinline__ int detect64(const void* edges, int n_nodes) {
  const long long* p = (const long long*)edges;
  int ok = 1;
#pragma unroll
  for (int i = 0; i < 8; ++i) {
    long long v = p[i];
    if (v < 0 || v >= n_nodes) ok = 0;
  }
  return ok;
}

// ---------------- prep: zeroing + x->bf16 cast + weight transposes ----------------

__device__ __forceinline__ void ttile(const float* __restrict__ src, int Nw,
                                      unsigned short* __restrict__ dst, int ldd,
                                      int rowoff, int coloff,
                                      int tileIdx, int tilesN, float (*tile)[33]) {
  int tk = tileIdx / tilesN, tn = tileIdx % tilesN;
  int k0 = tk * 32, n0 = tn * 32;
  int tx = threadIdx.x & 31, ty = threadIdx.x >> 5;
#pragma unroll
  for (int s = 0; s < 4; ++s)
    tile[ty + s * 8][tx] = src[(size_t)(k0 + ty + s * 8) * Nw + n0 + tx];
  __syncthreads();
#pragma unroll
  for (int s = 0; s < 4; ++s)
    dst[(size_t)(rowoff + n0 + ty + s * 8) * ldd + coloff + k0 + tx] =
        f2bf(tile[tx][ty + s * 8]);
}

__global__ void prep_kernel(int* deg, int* cursor, int n,
                            const float* __restrict__ x, unsigned short* __restrict__ xb,
                            int total4,
                            const float* __restrict__ w1_rel, const float* __restrict__ w1_root,
                            const float* __restrict__ w2_rel, const float* __restrict__ w2_root,
                            const float* __restrict__ wmu_rel, const float* __restrict__ wmu_root,
                            const float* __restrict__ wls_rel, const float* __restrict__ wls_root,
                            unsigned short* __restrict__ Bt1,
                            unsigned short* __restrict__ Bt2,
                            unsigned short* __restrict__ Bt3) {
  __shared__ float tile[32][33];
  int b = blockIdx.x;
  if (b >= 1408) {  // 640 cast blocks: x (fp32) -> xb (bf16), float4-wide
    int b4 = (b - 1408) * 1024;
#pragma unroll
    for (int s = 0; s < 4; ++s) {
      int i4 = b4 + s * 256 + threadIdx.x;
      if (i4 < total4) {
        float4 v = reinterpret_cast<const float4*>(x)[i4];
        ushort4 o;
        o.x = f2bf(v.x); o.y = f2bf(v.y); o.z = f2bf(v.z); o.w = f2bf(v.w);
        reinterpret_cast<ushort4*>(xb)[i4] = o;
      }
    }
    return;
  }
  if (b >= 1344) {  // 64 init blocks
    int i = (b - 1344) * blockDim.x + threadIdx.x;
    int stride = 64 * blockDim.x;
    for (int j = i; j < n; j += stride) { deg[j] = 0; cursor[j] = 0; }
    return;
  }
  if (b < 128)       ttile(w1_rel, 1024, Bt1, 256, 0, 0, b, 32, tile);
  else if (b < 256)  ttile(w1_root, 1024, Bt1, 256, 0, 128, b - 128, 32, tile);
  else if (b < 768)  ttile(w2_rel, 512, Bt2, 1024, 0, 0, b - 256, 16, tile);
  else if (b < 1280) ttile(w2_root, 512, Bt2, 1024, 512, 0, b - 768, 16, tile);
  else {
    int idx = (b - 1280) * 256 + threadIdx.x;  // 64 blocks * 256 = 16384 = 32*512
    int nn = idx >> 9, k = idx & 511;
    float v;
    if (nn < 8) v = wmu_rel[(size_t)k * 8 + nn];
    else if (nn < 16) v = wmu_root[(size_t)k * 8 + (nn - 8)];
    else if (nn < 24) v = wls_rel[(size_t)k * 8 + (nn - 16)];
    else v = wls_root[(size_t)k * 8 + (nn - 24)];
    Bt3[(size_t)nn * 512 + k] = f2bf(v);
  }
}

__device__ __forceinline__ int edge_at(const void* p, int is64, size_t idx) {
  return is64 ? (int)((const long long*)p)[idx] : ((const int*)p)[idx];
}

__global__ void count_kernel(const void* edges, int E, int n_nodes, int* deg) {
  int is64 = detect64(edges, n_nodes);
  int i = blockIdx.x * blockDim.x + threadIdx.x;
  int stride = gridDim.x * blockDim.x;
  for (int e = i; e < E; e += stride) {
    int d = edge_at(edges, is64, (size_t)E + e);
    atomicAdd(&deg[d], 1);
  }
}

__global__ void scan_kernel(const int* __restrict__ deg, int* __restrict__ rs,
                            float* __restrict__ invdeg, int n) {
  __shared__ int ssum[1024];
  int tid = threadIdx.x;
  int chunk = (n + 1023) >> 10;
  int start = tid * chunk;
  int end = min(start + chunk, n);
  int s = 0;
  for (int i = start; i < end; ++i) s += deg[i];
  ssum[tid] = s;
  __syncthreads();
  for (int off = 1; off < 1024; off <<= 1) {
    int t = (tid >= off) ? ssum[tid - off] : 0;
    __syncthreads();
    ssum[tid] += t;
    __syncthreads();
  }
  int run = (tid ? ssum[tid - 1] : 0);
  if (tid == 0) rs[0] = 0;
  for (int i = start; i < end; ++i) {
    int d = deg[i];
    run += d;
    rs[i + 1] = run;
    invdeg[i] = 1.0f / fmaxf((float)d, 1.0f);
  }
}

__global__ void fill_kernel(const void* edges, int E, int n_nodes,
                            const int* __restrict__ rs, int* cursor, int* col_src) {
  int is64 = detect64(edges, n_nodes);
  int i = blockIdx.x * blockDim.x + threadIdx.x;
  int stride = gridDim.x * blockDim.x;
  for (int e = i; e < E; e += stride) {
    int d = edge_at(edges, is64, (size_t)E + e);
    int s = edge_at(edges, is64, (size_t)e);
    int p = atomicAdd(&cursor[d], 1);
    col_src[rs[d] + p] = s;
  }
}

// ---------------- aggregation ----------------

// layer-1: A1[node] = [mean_j xb_j | xb_node], bf16 gather (4 nodes/block)
__global__ void agg1_kernel(const unsigned short* __restrict__ xb,
                            const int* __restrict__ rs, const int* __restrict__ cs,
                            const float* __restrict__ invdeg,
                            unsigned short* __restrict__ A1, int M) {
  int node = blockIdx.x * 4 + (threadIdx.x >> 6);
  if (node >= M) return;
  int c0 = (threadIdx.x & 63) * 2;
  float a0 = 0.f, a1 = 0.f;
  int e1 = rs[node + 1];
  for (int e = rs[node]; e < e1; ++e) {
    unsigned w = *reinterpret_cast<const unsigned*>(xb + (size_t)cs[e] * 128 + c0);
    a0 += bf2f((unsigned short)(w & 0xffff));
    a1 += bf2f((unsigned short)(w >> 16));
  }
  float inv = invdeg[node];
  unsigned root = *reinterpret_cast<const unsigned*>(xb + (size_t)node * 128 + c0);
  unsigned mean = (unsigned)f2bf(a0 * inv) | ((unsigned)f2bf(a1 * inv) << 16);
  *reinterpret_cast<unsigned*>(A1 + (size_t)node * 256 + c0) = mean;
  *reinterpret_cast<unsigned*>(A1 + (size_t)node * 256 + 128 + c0) = root;
}

// layer-2 combine, 4 nodes/block (256 thr), 16B per lane:
// h2[i][c] = relu( inv*sum_j P2[j][c] + P2[i][512+c] + b2[c] )
__global__ void agg2_kernel(const unsigned short* __restrict__ P2,
                            const int* __restrict__ rs, const int* __restrict__ cs,
                            const float* __restrict__ invdeg,
                            const float* __restrict__ b2,
                            unsigned short* __restrict__ h2, int M) {
  int node = blockIdx.x * 4 + (threadIdx.x >> 6);
  if (node >= M) return;
  int f0 = (threadIdx.x & 63) * 8;  // 64 lanes x 8 cols = 512
  float acc[8];
#pragma unroll
  for (int v = 0; v < 8; ++v) acc[v] = 0.f;
  int e1 = rs[node + 1];
  for (int e = rs[node]; e < e1; ++e) {
    int s = cs[e];
    uint4 w = *reinterpret_cast<const uint4*>(P2 + (size_t)s * 1024 + f0);
    acc[0] += bf2f((unsigned short)(w.x & 0xffff));
    acc[1] += bf2f((unsigned short)(w.x >> 16));
    acc[2] += bf2f((unsigned short)(w.y & 0xffff));
    acc[3] += bf2f((unsigned short)(w.y >> 16));
    acc[4] += bf2f((unsigned short)(w.z & 0xffff));
    acc[5] += bf2f((unsigned short)(w.z >> 16));
    acc[6] += bf2f((unsigned short)(w.w & 0xffff));
    acc[7] += bf2f((unsigned short)(w.w >> 16));
  }
  float inv = invdeg[node];
  uint4 wr = *reinterpret_cast<const uint4*>(P2 + (size_t)node * 1024 + 512 + f0);
  float rt[8] = {
    bf2f((unsigned short)(wr.x & 0xffff)), bf2f((unsigned short)(wr.x >> 16)),
    bf2f((unsigned short)(wr.y & 0xffff)), bf2f((unsigned short)(wr.y >> 16)),
    bf2f((unsigned short)(wr.z & 0xffff)), bf2f((unsigned short)(wr.z >> 16)),
    bf2f((unsigned short)(wr.w & 0xffff)), bf2f((unsigned short)(wr.w >> 16))};
  unsigned short o[8];
#pragma unroll
  for (int v = 0; v < 8; ++v)
    o[v] = f2bf(fmaxf(acc[v] * inv + rt[v] + b2[f0 + v], 0.f));
  uint4 pk;
  pk.x = (unsigned)o[0] | ((unsigned)o[1] << 16);
  pk.y = (unsigned)o[2] | ((unsigned)o[3] << 16);
  pk.z = (unsigned)o[4] | ((unsigned)o[5] << 16);
  pk.w = (unsigned)o[6] | ((unsigned)o[7] << 16);
  *reinterpret_cast<uint4*>(h2 + (size_t)node * 512 + f0) = pk;
}

// heads combine: P3 [Mpad][32] f32: cols 0-7 mu_rel, 8-15 mu_root, 16-23 ls_rel, 24-31 ls_root
__global__ void head_agg_kernel(const float* __restrict__ P3,
                                const int* __restrict__ rs, const int* __restrict__ cs,
                                const float* __restrict__ invdeg,
                                const float* __restrict__ bmu, const float* __restrict__ bls,
                                float* __restrict__ outmu, float* __restrict__ outls, int M) {
  int idx = blockIdx.x * blockDim.x + threadIdx.x;
  int node = idx >> 4;
  int c = idx & 15;
  if (node >= M) return;
  int relc = (c < 8) ? c : (16 + (c - 8));
  float acc = 0.f;
  int e1 = rs[node + 1];
  for (int e = rs[node]; e < e1; ++e) acc += P3[(size_t)cs[e] * 32 + relc];
  float v = acc * invdeg[node] + P3[(size_t)node * 32 + relc + 8]
          + ((c < 8) ? bmu[c] : bls[c - 8]);
  if (c < 8) outmu[(size_t)node * 8 + c] = v;
  else outls[(size_t)node * 8 + (c - 8)] = v;
}

// ------ 128x128 GEMM, 4 waves, ring-2, __syncthreads per step, swizzled ------
// (Frozen at plateau; best-of-13 structures at ~470 TF for this shape.)
__launch_bounds__(256, 4)
__global__ void gemm_db_kernel(const unsigned short* __restrict__ A, int lda,
                               const unsigned short* __restrict__ Bt, int ldb,
                               const float* __restrict__ bias,
                               void* __restrict__ outp, int ldo,
                               int M, int N, int K, int relu, int out_f32, int gx) {
  __shared__ unsigned short As[2 * 4096];
  __shared__ unsigned short Bs[2 * 4096];
  const int tid = threadIdx.x;
  const int lane = tid & 63;
  const int w = tid >> 6;
  const int wr = w >> 1, wc = w & 1;
  const int lr = lane & 15, lk = lane >> 4;
  const int sw8 = (lk ^ ((lr >> 1) & 3)) * 8;

  int nwg = gridDim.x, orig = blockIdx.x;
  int q = nwg >> 3, r = nwg & 7;
  int xcd = orig & 7, lid = orig >> 3;
  int swz = (xcd < r ? xcd * (q + 1) : r * (q + 1) + (xcd - r) * q) + lid;
  int m0 = (swz / gx) * 128, n0 = (swz % gx) * 128;

  f32x4 acc[4][4];
#pragma unroll
  for (int i = 0; i < 4; ++i)
#pragma unroll
    for (int j = 0; j < 4; ++j) acc[i][j] = (f32x4)0.0f;

  const int r0 = tid >> 2;
  const int slog = ((tid & 3) ^ ((r0 >> 1) & 3)) * 8;
  const unsigned short* gA = A + (size_t)(m0 + r0) * lda + slog;
  const unsigned short* gB = Bt + (size_t)(n0 + r0) * ldb + slog;
  const size_t a64 = (size_t)64 * lda, b64 = (size_t)64 * ldb;
  unsigned short* wa = As + w * 512;
  unsigned short* wb = Bs + w * 512;

  auto STG = [&](int s, int t) {
    const unsigned short* a = gA + (size_t)t * 32;
    const unsigned short* b = gB + (size_t)t * 32;
    gl_lds16(a, wa + s * 4096);
    gl_lds16(a + a64, wa + s * 4096 + 2048);
    gl_lds16(b, wb + s * 4096);
    gl_lds16(b + b64, wb + s * 4096 + 2048);
  };

  const int nt = K >> 5;
  STG(0, 0);
  __syncthreads();

  int buf = 0;
  for (int t = 0; t < nt; ++t) {
    if (t + 1 < nt) STG(buf ^ 1, t + 1);
    const unsigned short* as_ = As + buf * 4096;
    const unsigned short* bs_ = Bs + buf * 4096;
    short8 af[4], bf[4];
#pragma unroll
    for (int i = 0; i < 4; ++i) {
      af[i] = *reinterpret_cast<const short8*>(&as_[(wr * 64 + i * 16 + lr) * 32 + sw8]);
      bf[i] = *reinterpret_cast<const short8*>(&bs_[(wc * 64 + i * 16 + lr) * 32 + sw8]);
    }
    __builtin_amdgcn_s_setprio(1);
#pragma unroll
    for (int i = 0; i < 4; ++i)
#pragma unroll
      for (int j = 0; j < 4; ++j)
        acc[i][j] = __builtin_amdgcn_mfma_f32_16x16x32_bf16(af[i], bf[j], acc[i][j], 0, 0, 0);
    __builtin_amdgcn_s_setprio(0);
    if (t + 1 < nt) __syncthreads();
    buf ^= 1;
  }

#pragma unroll
  for (int i = 0; i < 4; ++i) {
    int row_b = m0 + wr * 64 + i * 16 + lk * 4;
#pragma unroll
    for (int j = 0; j < 4; ++j) {
      int col = n0 + wc * 64 + j * 16 + lr;
      float bv = bias ? bias[col] : 0.f;
#pragma unroll
      for (int rr = 0; rr < 4; ++rr) {
        int row = row_b + rr;
        if (row < M) {
          float v = acc[i][j][rr] + bv;
          if (relu) v = fmaxf(v, 0.f);
          if (out_f32) ((float*)outp)[(size_t)row * ldo + col] = v;
          else ((unsigned short*)outp)[(size_t)row * ldo + col] = f2bf(v);
        }
      }
    }
  }
}

// ------ heads GEMM: C[M][32] = h2[M][512] @ Bt3[32][512]^T, fp32 out ------
__launch_bounds__(256, 3)
__global__ void gemm_heads_kernel(const unsigned short* __restrict__ A,
                                  const unsigned short* __restrict__ Bt3,
                                  float* __restrict__ P3, int M) {
  __shared__ unsigned short Bs[16 * 1024];
  __shared__ unsigned short As[2 * 4096];
  const int tid = threadIdx.x;
  const int lane = tid & 63;
  const int w = tid >> 6;
  const int lr = lane & 15, lk = lane >> 4;
  const int sw8 = (lk ^ ((lr >> 1) & 3)) * 8;

  int nwg = gridDim.x, orig = blockIdx.x;
  int q = nwg >> 3, r = nwg & 7;
  int xcd = orig & 7, lid = orig >> 3;
  int swz = (xcd < r ? xcd * (q + 1) : r * (q + 1) + (xcd - r) * q) + lid;
  int m0 = swz * 128;

  for (int i = 0; i < 8; ++i) {
    int j = i * 256 + tid;
    int n = j >> 6, p = j & 63;
    int x = (n >> 1) & 3;
    uint4 v = *reinterpret_cast<const uint4*>(Bt3 + (size_t)n * 512 + ((p & ~3) | ((p & 3) ^ x)) * 8);
    *reinterpret_cast<uint4*>(&Bs[(p >> 2) * 1024 + n * 32 + (p & 3) * 8]) = v;
  }

  f32x4 acc[2][2];
#pragma unroll
  for (int i = 0; i < 2; ++i)
#pragma unroll
    for (int j = 0; j < 2; ++j) acc[i][j] = (f32x4)0.0f;

  const int r0 = tid >> 2;
  const int slog = ((tid & 3) ^ ((r0 >> 1) & 3)) * 8;
  const unsigned short* gA = A + (size_t)(m0 + r0) * 512 + slog;
  const size_t a64 = (size_t)64 * 512;
  unsigned short* wa = As + w * 512;

  auto STG = [&](int s, int t) {
    const unsigned short* a = gA + (size_t)t * 32;
    gl_lds16(a, wa + s * 4096);
    gl_lds16(a + a64, wa + s * 4096 + 2048);
  };

  STG(0, 0);
  __syncthreads();

  int buf = 0;
  const int nt = 16;
  for (int t = 0; t < nt; ++t) {
    if (t + 1 < nt) STG(buf ^ 1, t + 1);
    const unsigned short* as_ = As + buf * 4096;
    short8 af[2], bf[2];
#pragma unroll
    for (int i = 0; i < 2; ++i) {
      af[i] = *reinterpret_cast<const short8*>(&as_[(w * 32 + i * 16 + lr) * 32 + sw8]);
      bf[i] = *reinterpret_cast<const short8*>(&Bs[t * 1024 + (i * 16 + lr) * 32 + sw8]);
    }
#pragma unroll
    for (int i = 0; i < 2; ++i)
#pragma unroll
      for (int j = 0; j < 2; ++j)
        acc[i][j] = __builtin_amdgcn_mfma_f32_16x16x32_bf16(af[i], bf[j], acc[i][j], 0, 0, 0);
    if (t + 1 < nt) __syncthreads();
    buf ^= 1;
  }

#pragma unroll
  for (int i = 0; i < 2; ++i) {
    int row_b = m0 + w * 32 + i * 16 + lk * 4;
#pragma unroll
    for (int j = 0; j < 2; ++j) {
      int col = j * 16 + lr;
#pragma unroll
      for (int rr = 0; rr < 4; ++rr) {
        int row = row_b + rr;
        if (row < M) P3[(size_t)row * 32 + col] = acc[i][j][rr];
      }
    }
  }
}

// ---------------- host ----------------

extern "C" void kernel_launch(void* const* d_in, const int* in_sizes, int n_in,
                              void* d_out, int out_size, void* d_ws, size_t ws_size,
                              hipStream_t stream) {
  const float* x = (const float*)d_in[0];
  const void* edge = d_in[1];
  const float* w1_rel = (const float*)d_in[2];
  const float* b1 = (const float*)d_in[3];
  const float* w1_root = (const float*)d_in[4];
  const float* w2_rel = (const float*)d_in[5];
  const float* b2 = (const float*)d_in[6];
  const float* w2_root = (const float*)d_in[7];
  const float* wmu_rel = (const float*)d_in[8];
  const float* bmu = (const float*)d_in[9];
  const float* wmu_root = (const float*)d_in[10];
  const float* wls_rel = (const float*)d_in[11];
  const float* bls = (const float*)d_in[12];
  const float* wls_root = (const float*)d_in[13];

  const int FIN = 128, H1 = 1024, H2 = 512;
  const int M = in_sizes[0] / FIN;   // 20000
  const int E = in_sizes[1] / 2;     // 160000
  const int Mpad = ((M + 127) / 128) * 128;   // 20096
  const int gy = Mpad / 128;                  // 157

  char* ws = (char*)d_ws;
  size_t off = 0;
  auto alloc = [&](size_t bytes) -> char* {
    char* p = ws + off;
    off = (off + bytes + 255) & ~(size_t)255;
    return p;
  };
  int* deg = (int*)alloc((size_t)M * 4);
  int* cursor = (int*)alloc((size_t)M * 4);
  int* rs = (int*)alloc((size_t)(M + 1) * 4);
  float* invdeg = (float*)alloc((size_t)M * 4);
  int* cs = (int*)alloc((size_t)E * 4);
  unsigned short* xb = (unsigned short*)alloc((size_t)M * 128 * 2);
  unsigned short* A1 = (unsigned short*)alloc((size_t)Mpad * 256 * 2);
  unsigned short* h1 = (unsigned short*)alloc((size_t)Mpad * 1024 * 2);
  unsigned short* P2 = (unsigned short*)alloc((size_t)Mpad * 1024 * 2);
  unsigned short* h2 = (unsigned short*)alloc((size_t)Mpad * 512 * 2);
  float* P3 = (float*)alloc((size_t)Mpad * 32 * 4);
  unsigned short* Bt1 = (unsigned short*)alloc((size_t)H1 * 256 * 2);
  unsigned short* Bt2 = (unsigned short*)alloc((size_t)1024 * 1024 * 2);
  unsigned short* Bt3 = (unsigned short*)alloc((size_t)32 * 512 * 2);

  // prep: zero deg/cursor + x->bf16 + all weight transposes (one launch)
  prep_kernel<<<2048, 256, 0, stream>>>(deg, cursor, M,
                                        x, xb, M * FIN / 4,
                                        w1_rel, w1_root, w2_rel, w2_root,
                                        wmu_rel, wmu_root, wls_rel, wls_root,
                                        Bt1, Bt2, Bt3);
  count_kernel<<<256, 256, 0, stream>>>(edge, E, M, deg);
  scan_kernel<<<1, 1024, 0, stream>>>(deg, rs, invdeg, M);
  fill_kernel<<<256, 256, 0, stream>>>(edge, E, M, rs, cursor, cs);

  // Layer 1: A1 = [mean(xb) | xb]; h1 = relu(A1 @ Bt1^T + b1)
  agg1_kernel<<<(M + 3) / 4, 256, 0, stream>>>(xb, rs, cs, invdeg, A1, M);
  gemm_db_kernel<<<(H1 / 128) * gy, 256, 0, stream>>>(
      A1, 256, Bt1, 256, b1, h1, 1024, M, H1, 256, 1, 0, H1 / 128);

  // Layer 2 (commuted): P2 = h1 @ [w2_rel | w2_root]; h2 = relu(mean_agg(P2_rel) + P2_root + b2)
  gemm_db_kernel<<<(1024 / 128) * gy, 256, 0, stream>>>(
      h1, 1024, Bt2, 1024, nullptr, P2, 1024, M, 1024, 1024, 0, 0, 1024 / 128);
  agg2_kernel<<<(M + 3) / 4, 256, 0, stream>>>(P2, rs, cs, invdeg, b2, h2, M);

  // Heads (commuted): P3 = h2 @ [4 head mats]^T; out = mean_agg(P3_rel) + P3_root + bias
  gemm_heads_kernel<<<gy, 256, 0, stream>>>(h2, Bt3, P3, M);
  float* outmu = (float*)d_out;
  float* outls = outmu + (size_t)M * 8;
  head_agg_kernel<<<(M * 16 + 255) / 256, 256, 0, stream>>>(
      P3, rs, cs, invdeg, bmu, bls, outmu, outls, M);
}